// Round 7
// baseline (451.821 us; speedup 1.0000x reference)
//
#include <hip/hip_runtime.h>

typedef unsigned int u32;
typedef unsigned long long u64;
typedef unsigned char u8;

#define NB 4
#define T_ANCH 261120
#define NCAND 2048          // candidates per image (4 levels x 512)
#define KSEL 512
#define POSTN 512
#define LOG_MAXF 4.135166556742356f
#define NMS_TH 0.7f
#define LVL_OFF_F 8192.0f
#define BINS 4096           // top-12 bits of mono32
#define EQCAP 8192          // tie-bin capacity (expected ~300-700 occupants)
#define PAIR_CAP (1u<<20)   // 1M compacted pairs (observed ~17k -> 60x margin)

__device__ __forceinline__ u32 mono32(float f){
  u32 u = __float_as_uint(f);
  return (u & 0x80000000u) ? ~u : (u | 0x80000000u);
}
__device__ __forceinline__ int lvl_hw(int lvl){ return 65536 >> (2*lvl); }
__device__ __forceinline__ int lvl_off(int lvl){
  return (lvl>0?196608:0) + (lvl>1?49152:0) + (lvl>2?12288:0);
}

// ---------------------------------------------------------------------------
// K1: exact top-512 per (image, level) by key (mono(obj)<<32 | ~j) where j is
// the PERMUTED index (j = pix*3 + a). See R4 notes.
// ---------------------------------------------------------------------------
__global__ __launch_bounds__(1024) void k1_topk(
    const float* __restrict__ o0, const float* __restrict__ o1,
    const float* __restrict__ o2, const float* __restrict__ o3,
    int* __restrict__ cand_j)
{
  int bid = blockIdx.x;
  int b = bid >> 2, lvl = bid & 3;
  const float* ob = (lvl==0)?o0 : (lvl==1)?o1 : (lvl==2)?o2 : o3;
  int hw = lvl_hw(lvl);
  int size = 3*hw;                       // 196608 / 49152 / 12288 / 3072
  const float* base = ob + (size_t)b*size;
  const float4* b4 = (const float4*)base;  // size % 4 == 0, 16B-aligned
  int n4 = size >> 2;

  __shared__ u32 hist[BINS];
  __shared__ u64 eqbuf[EQCAP];
  __shared__ u32 coarse[64];
  __shared__ u32 s_b0, s_cntAbove, s_eqn, s_emit;

  int t = threadIdx.x;

  for (int i = t; i < BINS; i += 1024) hist[i] = 0;
  if (t == 0){ s_eqn = 0; s_emit = 0; }
  __syncthreads();

  // ---- Pass A: histogram of top-12 bits (value-only; order-independent) ----
  for (int i = t; i < n4; i += 1024){
    float4 v = b4[i];
    atomicAdd(&hist[mono32(v.x) >> 20], 1u);
    atomicAdd(&hist[mono32(v.y) >> 20], 1u);
    atomicAdd(&hist[mono32(v.z) >> 20], 1u);
    atomicAdd(&hist[mono32(v.w) >> 20], 1u);
  }
  __syncthreads();

  // ---- Coarse sums, then serial two-level descending walk ----
  if (t < 64){
    u32 s = 0;
    for (int z = 0; z < 64; ++z) s += hist[t*64 + z];
    coarse[t] = s;
  }
  __syncthreads();
  if (t == 0){
    u32 acc = 0;
    int cb = 63;
    while (acc + coarse[cb] < (u32)KSEL){ acc += coarse[cb]; --cb; }
    int z = cb*64 + 63;
    while (acc + hist[z] < (u32)KSEL){ acc += hist[z]; --z; }
    s_b0 = (u32)z;          // bin containing the 512th-largest key
    s_cntAbove = acc;       // count of elements in bins > b0  (< 512)
  }
  __syncthreads();
  u32 b0v = s_b0, cA = s_cntAbove;

  // ---- Pass B: classify (emit PERMUTED index j = (pix+q)*3 + a) ----
  for (int i = t; i < n4; i += 1024){
    float4 v = b4[i];
    int L = i << 2;                 // linear base index (= a*hw + pix)
    int a = L / hw;                 // same for all 4 lanes (hw % 4 == 0)
    int pix = L - a*hw;
    int j0 = pix*3 + a;             // permuted index of element q is j0 + 3q
    u32 m0 = mono32(v.x), m1 = mono32(v.y), m2 = mono32(v.z), m3 = mono32(v.w);
    u32 bb0 = m0 >> 20, bb1 = m1 >> 20, bb2 = m2 >> 20, bb3 = m3 >> 20;
    if (bb0 > b0v){ u32 s = atomicAdd(&s_emit,1u); if (s < (u32)KSEL) cand_j[bid*KSEL+s] = j0; }
    else if (bb0 == b0v){ u32 s = atomicAdd(&s_eqn,1u); if (s < (u32)EQCAP) eqbuf[s] = ((u64)m0<<32) | (u32)(~(u32)j0); }
    if (bb1 > b0v){ u32 s = atomicAdd(&s_emit,1u); if (s < (u32)KSEL) cand_j[bid*KSEL+s] = j0+3; }
    else if (bb1 == b0v){ u32 s = atomicAdd(&s_eqn,1u); if (s < (u32)EQCAP) eqbuf[s] = ((u64)m1<<32) | (u32)(~(u32)(j0+3)); }
    if (bb2 > b0v){ u32 s = atomicAdd(&s_emit,1u); if (s < (u32)KSEL) cand_j[bid*KSEL+s] = j0+6; }
    else if (bb2 == b0v){ u32 s = atomicAdd(&s_eqn,1u); if (s < (u32)EQCAP) eqbuf[s] = ((u64)m2<<32) | (u32)(~(u32)(j0+6)); }
    if (bb3 > b0v){ u32 s = atomicAdd(&s_emit,1u); if (s < (u32)KSEL) cand_j[bid*KSEL+s] = j0+9; }
    else if (bb3 == b0v){ u32 s = atomicAdd(&s_eqn,1u); if (s < (u32)EQCAP) eqbuf[s] = ((u64)m3<<32) | (u32)(~(u32)(j0+9)); }
  }
  __syncthreads();

  // ---- Tie resolution: O(n^2) exact rank-select ----
  u32 n = s_eqn < (u32)EQCAP ? s_eqn : (u32)EQCAP;
  u32 k = (u32)KSEL - cA;                 // >= 1, <= 512
  for (u32 i = t; i < n; i += 1024){
    u64 ki = eqbuf[i];
    u32 r = 0;
    for (u32 mm = 0; mm < n; ++mm) r += (eqbuf[mm] > ki) ? 1u : 0u;
    if (r < k){
      u32 s = atomicAdd(&s_emit, 1u);
      if (s < (u32)KSEL) cand_j[bid*KSEL + s] = (int)(~(u32)ki);
    }
  }
}

// ---------------------------------------------------------------------------
// K2: decode the 8192 selected candidates; build sort keys.
// ---------------------------------------------------------------------------
__global__ __launch_bounds__(256) void k2_decode(
    const float* __restrict__ o0, const float* __restrict__ o1,
    const float* __restrict__ o2, const float* __restrict__ o3,
    const float* __restrict__ d0, const float* __restrict__ d1,
    const float* __restrict__ d2, const float* __restrict__ d3,
    const float* __restrict__ anchors,
    const int* __restrict__ cand_j,
    float* __restrict__ cscore, u32* __restrict__ csmono,
    u64* __restrict__ ctb, float* __restrict__ cbox, u8* __restrict__ cvalid)
{
  int c = blockIdx.x*256 + threadIdx.x;
  if (c >= NB*NCAND) return;
  int pair = c >> 9;          // (b,lvl) pair index
  int b = pair >> 2, lvl = pair & 3;
  int j = cand_j[c];
  int hw = lvl_hw(lvl);
  u32 pix = (u32)j / 3u;
  u32 a = (u32)j - pix*3u;
  const float* ob = (lvl==0)?o0 : (lvl==1)?o1 : (lvl==2)?o2 : o3;
  const float* dl = (lvl==0)?d0 : (lvl==1)?d1 : (lvl==2)?d2 : d3;

  float ov = ob[(size_t)(b*3 + (int)a)*hw + pix];
  size_t dbase = ((size_t)(b*3 + (int)a)*6)*(size_t)hw + pix;
  float dx  = dl[dbase + 0*(size_t)hw];
  float dy  = dl[dbase + 1*(size_t)hw];
  float dw  = dl[dbase + 2*(size_t)hw];
  float dh  = dl[dbase + 3*(size_t)hw];
  float dsn = dl[dbase + 4*(size_t)hw];
  float dcs = dl[dbase + 5*(size_t)hw];
  int tt = lvl_off(lvl) + j;
  const float* an = anchors + ((size_t)b*T_ANCH + tt)*5;
  float ax=an[0], ay=an[1], aw=an[2], ah=an[3], aa=an[4];
  dw = fminf(dw, LOG_MAXF); dh = fminf(dh, LOG_MAXF);
  float cx = ax + dx*aw;
  float cy = ay + dy*ah;
  float w  = aw * expf(dw);
  float h  = ah * expf(dh);
  float ang = aa + atan2f(dsn, dcs);
  double sd = 1.0 / (1.0 + exp(-(double)ov));
  float sc = (float)sd;
  bool valid = (w >= 1e-3f) && (h >= 1e-3f) && (sc >= 0.0f);
  cscore[c] = sc;
  csmono[c] = valid ? mono32(sc) : 0u;        // invalid => -inf (stable-sorted by tb)
  // tiebreak: level asc, obj desc, idx asc  (== reference positional order)
  ctb[c] = ((u64)lvl << 50) | ((u64)(u32)(~mono32(ov)) << 18) | (u64)(u32)j;
  cvalid[c] = valid ? 1 : 0;
  float* bb = cbox + (size_t)c*5;
  bb[0]=cx; bb[1]=cy; bb[2]=w; bb[3]=h; bb[4]=ang;
}

// ---------------------------------------------------------------------------
// K3: per-image stable-equivalent sort (score desc, tb asc) via bitonic in LDS,
// then gather sorted arrays + offset corners / AABB / area geometry.
// ---------------------------------------------------------------------------
__global__ __launch_bounds__(1024) void k3_sort(
    const u32* __restrict__ csmono, const u64* __restrict__ ctb,
    const float* __restrict__ cscore, const float* __restrict__ cbox,
    const u8* __restrict__ cvalid,
    float* __restrict__ sscore, float* __restrict__ sbox,
    float* __restrict__ geom, u8* __restrict__ svalid)
{
  int b = blockIdx.x;
  __shared__ u32 sm[NCAND];
  __shared__ u64 stb[NCAND];
  __shared__ u32 sid[NCAND];
  for (int k = threadIdx.x; k < NCAND; k += 1024){
    sm[k]  = csmono[b*NCAND + k];
    stb[k] = ctb[b*NCAND + k];
    sid[k] = (u32)k;
  }
  __syncthreads();
  for (int kk = 2; kk <= NCAND; kk <<= 1){
    for (int jj = kk >> 1; jj > 0; jj >>= 1){
      for (int i = threadIdx.x; i < NCAND; i += 1024){
        int ixj = i ^ jj;
        if (ixj > i){
          bool dirAsc = ((i & kk) == 0);
          u32 s1 = sm[i], s2 = sm[ixj];
          u64 t1 = stb[i], t2 = stb[ixj];
          bool before_ixj = (s2 > s1) || (s2 == s1 && t2 < t1);
          bool sw = dirAsc ? before_ixj : !before_ixj;
          if (sw){
            sm[i]=s2; sm[ixj]=s1;
            stb[i]=t2; stb[ixj]=t1;
            u32 tmp = sid[i]; sid[i]=sid[ixj]; sid[ixj]=tmp;
          }
        }
      }
      __syncthreads();
    }
  }
  for (int k = threadIdx.x; k < NCAND; k += 1024){
    int id = (int)sid[k];
    int gsrc = b*NCAND + id;
    int gdst = b*NCAND + k;
    float scv = cscore[gsrc];
    sscore[gdst] = scv;
    svalid[gdst] = cvalid[gsrc];
    float b0 = cbox[(size_t)gsrc*5+0], b1 = cbox[(size_t)gsrc*5+1];
    float b2 = cbox[(size_t)gsrc*5+2], b3 = cbox[(size_t)gsrc*5+3];
    float b4 = cbox[(size_t)gsrc*5+4];
    float* sb = sbox + (size_t)gdst*5;
    sb[0]=b0; sb[1]=b1; sb[2]=b2; sb[3]=b3; sb[4]=b4;
    int lvl = (int)((stb[k] >> 50) & 3ull);
    float offv = (float)lvl * LVL_OFF_F;
    float cx = b0 + offv, cy = b1 + offv, w=b2, h=b3, ang=b4;
    float cc = cosf(ang), sn = sinf(ang);
    float hx = 0.5f*w, hy = 0.5f*h;
    float x0 = cx + hx*cc - hy*sn, y0 = cy + hx*sn + hy*cc;
    float x1 = cx - hx*cc - hy*sn, y1 = cy - hx*sn + hy*cc;
    float x2 = cx - hx*cc + hy*sn, y2 = cy - hx*sn - hy*cc;
    float x3 = cx + hx*cc + hy*sn, y3 = cy + hx*sn - hy*cc;
    float minx = fminf(fminf(x0,x1),fminf(x2,x3));
    float maxx = fmaxf(fmaxf(x0,x1),fmaxf(x2,x3));
    float miny = fminf(fminf(y0,y1),fminf(y2,y3));
    float maxy = fmaxf(fmaxf(y0,y1),fmaxf(y2,y3));
    float* g = geom + (size_t)gdst*16;
    g[0]=minx; g[1]=maxx; g[2]=miny; g[3]=maxy; g[4]=w*h;
    g[5]=x0; g[6]=y0; g[7]=x1; g[8]=y1; g[9]=x2; g[10]=y2; g[11]=x3; g[12]=y3;
  }
}

// ---------------------------------------------------------------------------
// K4a: AABB filter + mask zeroing + compacted pair list (LDS-aggregated
// atomics). AABB-disjoint => inter==0 => bit=false (decision-safe reject).
// ---------------------------------------------------------------------------
__global__ __launch_bounds__(256) void k4a_aabb(
    const float* __restrict__ geom, u64* __restrict__ mask,
    u32* __restrict__ list, u32* __restrict__ gcount)
{
  int gt = blockIdx.x*256 + threadIdx.x;
  int img = gt >> 22;
  int rem = gt & ((1<<22)-1);
  int i = rem >> 11;
  int j = rem & (NCAND-1);
  // zero this block's 4 mask words (one per 64-j group)
  if ((threadIdx.x & 63) == 0)
    mask[((size_t)(img*NCAND + i))*32 + (j >> 6)] = 0ull;
  __shared__ u32 lcnt, lbase;
  if (threadIdx.x == 0) lcnt = 0;
  __syncthreads();
  bool pass = false;
  if (j > i){
    const float4 gi = *(const float4*)(geom + ((size_t)(img*NCAND + i))*16);
    const float4 gj = *(const float4*)(geom + ((size_t)(img*NCAND + j))*16);
    pass = !(gi.x > gj.y || gj.x > gi.y || gi.z > gj.w || gj.z > gi.w);
  }
  u32 slot = 0;
  if (pass) slot = atomicAdd(&lcnt, 1u);
  __syncthreads();
  if (threadIdx.x == 0 && lcnt) lbase = atomicAdd(gcount, lcnt);
  __syncthreads();
  if (pass){
    u32 idx = lbase + slot;
    if (idx < PAIR_CAP) list[idx] = (u32)gt;
  }
}

// ---------------------------------------------------------------------------
// K4b: dense clip over the compacted list; scatter bits via atomicOr.
// ---------------------------------------------------------------------------
__device__ __forceinline__ void emit_pt(float* ox, float* oy, int oc, float x, float y){
  #pragma unroll
  for (int s = 0; s < 8; ++s) if (s == oc){ ox[s] = x; oy[s] = y; }
}

__device__ float quad_inter(const float* ca, const float* cb){
  float px[8], py[8];
  #pragma unroll
  for (int q = 0; q < 8; ++q){ px[q]=0.f; py[q]=0.f; }
  #pragma unroll
  for (int q = 0; q < 4; ++q){ px[q]=ca[2*q]; py[q]=ca[2*q+1]; }
  int cnt = 4;
  #pragma unroll
  for (int e = 0; e < 4; ++e){
    float p1x = cb[2*e],         p1y = cb[2*e+1];
    float p2x = cb[(2*e+2)&7],   p2y = cb[(2*e+3)&7];
    float ex = p2x-p1x, ey = p2y-p1y;
    float d[8];
    #pragma unroll
    for (int q = 0; q < 8; ++q) d[q] = ex*(py[q]-p1y) - ey*(px[q]-p1x);
    float ox[8], oy[8];
    #pragma unroll
    for (int q = 0; q < 8; ++q){ ox[q]=0.f; oy[q]=0.f; }
    int oc = 0;
    #pragma unroll
    for (int q = 0; q < 8; ++q){
      if (q < cnt){
        bool last = (q+1 >= cnt);
        float dn  = last ? d[0]  : d[(q+1)&7];
        bool in0 = (d[q] >= 0.0f), in1 = (dn >= 0.0f);
        if (in0){ emit_pt(ox,oy,oc,px[q],py[q]); oc++; }
        if (in0 != in1){
          float pnx = last ? px[0] : px[(q+1)&7];
          float pny = last ? py[0] : py[(q+1)&7];
          float den = d[q] - dn;
          float t = d[q] / ((den == 0.0f) ? 1.0f : den);
          emit_pt(ox,oy,oc, px[q] + t*(pnx-px[q]), py[q] + t*(pny-py[q]));
          oc++;
        }
      }
    }
    cnt = (oc > 8) ? 8 : oc;
    #pragma unroll
    for (int q = 0; q < 8; ++q){ px[q]=ox[q]; py[q]=oy[q]; }
  }
  if (cnt < 3) return 0.0f;
  float s = 0.0f;
  #pragma unroll
  for (int q = 0; q < 8; ++q){
    if (q < cnt){
      bool last = (q+1 >= cnt);
      float pnx = last ? px[0] : px[(q+1)&7];
      float pny = last ? py[0] : py[(q+1)&7];
      s += px[q]*pny - pnx*py[q];
    }
  }
  return 0.5f*fabsf(s);
}

__global__ __launch_bounds__(256) void k4b_clip(
    const float* __restrict__ geom, const u32* __restrict__ list,
    const u32* __restrict__ gcount, u64* __restrict__ mask)
{
  u32 count = *gcount;
  if (count > PAIR_CAP) count = PAIR_CAP;
  for (u32 idx = blockIdx.x*256 + threadIdx.x; idx < count; idx += gridDim.x*256){
    u32 gt = list[idx];
    int img = (int)(gt >> 22);
    int rem = (int)(gt & ((1u<<22)-1));
    int i = rem >> 11;
    int j = rem & (NCAND-1);
    const float* gi = geom + ((size_t)(img*NCAND + i))*16;
    const float* gj = geom + ((size_t)(img*NCAND + j))*16;
    float inter = quad_inter(gi+5, gj+5);
    float iou = inter / (gi[4] + gj[4] - inter + 1e-7f);
    if (iou > NMS_TH)
      atomicOr(&mask[((size_t)(img*NCAND + i))*32 + (j >> 6)], 1ull << (j & 63));
  }
}

// ---------------------------------------------------------------------------
// K5: sequential greedy suppression, sup in wave-0 registers, early exit at
// the 512th kept row (see R6 notes).
// ---------------------------------------------------------------------------
__global__ __launch_bounds__(1024) void k5_nms_out(
    const u64* __restrict__ mask, const u8* __restrict__ svalid,
    const float* __restrict__ sbox, const float* __restrict__ sscore,
    float* __restrict__ out)
{
  int b = blockIdx.x;
  __shared__ u64 buf[2][128*32];      // 64 KB double buffer
  __shared__ u64 s_kept[32];
  __shared__ u32 pref[32];
  __shared__ u32 s_done, s_R;
  int t = threadIdx.x;
  int wid = t >> 6, lane = t & 63;

  if (t == 0){ s_done = 0; s_R = NCAND - 1; }

  // sup init from svalid: lane l (l<32) builds word l; lanes 32-63 mirror.
  u32 slo = 0, shi = 0;
  if (wid == 0){
    int wl = lane & 31;
    u64 w = 0;
    for (int q = 0; q < 64; ++q)
      if (!svalid[b*NCAND + wl*64 + q]) w |= (1ull << q);
    slo = (u32)w; shi = (u32)(w >> 32);
  }
  // preload chunk 0 (all waves)
  {
    const u64* src = mask + ((size_t)b*NCAND)*32;
    for (int x = t; x < 128*32; x += 1024) buf[0][x] = src[x];
  }
  __syncthreads();

  u32 kcnt = 0;
  bool stopped = false;
  for (int c = 0; c < 16; ++c){
    if (wid != 0){
      if (c + 1 < 16){
        const u64* src = mask + ((size_t)(b*NCAND + (c+1)*128))*32;
        for (int x = t - 64; x < 128*32; x += (1024 - 64))
          buf[(c+1)&1][x] = src[x];
      }
    } else if (!stopped){
      const u64* ch = buf[c&1];
      for (int r8 = 0; r8 < 128 && !stopped; r8 += 8){
        u64 v[8];
        #pragma unroll
        for (int q = 0; q < 8; ++q) v[q] = ch[(r8+q)*32 + (lane & 31)];
        #pragma unroll
        for (int q = 0; q < 8; ++q){
          int gi = c*128 + r8 + q;
          int wi = gi >> 6;                       // wave-uniform
          u32 wlo = (u32)__builtin_amdgcn_readlane((int)slo, wi);
          u32 whi = (u32)__builtin_amdgcn_readlane((int)shi, wi);
          u64 w = ((u64)whi << 32) | wlo;
          u32 keep = (u32)((~w >> (gi & 63)) & 1ull);
          u64 vm = v[q] & (0ull - (u64)keep);     // branchless: keep ? v : 0
          slo |= (u32)vm; shi |= (u32)(vm >> 32);
          kcnt += keep;
          if (kcnt >= (u32)POSTN){                // 512th keep -> stop
            if (lane == 0){ s_done = 1; s_R = (u32)gi; }
            stopped = true;
            break;
          }
        }
      }
    }
    __syncthreads();
    if (s_done) break;
    __syncthreads();
  }
  // publish kept words, range-masked to rows <= R
  if (wid == 0 && lane < 32){
    u32 Rv = s_R;
    int lo_row = (int)lane * 64;
    u64 sup = ((u64)shi << 32) | slo;
    u64 rmask;
    if (lo_row + 63 <= (int)Rv) rmask = ~0ull;
    else if (lo_row > (int)Rv)  rmask = 0ull;
    else                        rmask = (1ull << ((int)Rv - lo_row + 1)) - 1ull;
    s_kept[lane] = (~sup) & rmask;
  }
  __syncthreads();

  // zero-fill this image's output (d_out is poisoned before every launch)
  for (int x = t; x < POSTN*5; x += 1024) out[(size_t)b*POSTN*5 + x] = 0.0f;
  for (int x = t; x < POSTN;   x += 1024) out[(size_t)NB*POSTN*5 + b*POSTN + x] = 0.0f;
  if (t < 32) pref[t] = (u32)__popcll(s_kept[t]);
  __syncthreads();
  if (t == 0){
    u32 run = 0;
    for (int w = 0; w < 32; ++w){ u32 tv = pref[w]; pref[w] = run; run += tv; }
  }
  __syncthreads();
  for (int i = t; i < NCAND; i += 1024){
    u64 kw = s_kept[i >> 6];
    if ((kw >> (i & 63)) & 1ull){
      u32 rank = pref[i >> 6] + (u32)__popcll(kw & ((1ull << (i & 63)) - 1ull));
      if (rank < POSTN){
        const float* bp = sbox + ((size_t)(b*NCAND + i))*5;
        float* op = out + ((size_t)(b*POSTN + rank))*5;
        op[0]=bp[0]; op[1]=bp[1]; op[2]=bp[2]; op[3]=bp[3]; op[4]=bp[4];
        out[(size_t)NB*POSTN*5 + b*POSTN + rank] = sscore[b*NCAND + i];
      }
    }
  }
}

// ---------------------------------------------------------------------------
extern "C" void kernel_launch(void* const* d_in, const int* in_sizes, int n_in,
                              void* d_out, int out_size, void* d_ws, size_t ws_size,
                              hipStream_t stream)
{
  (void)out_size; (void)ws_size;
  const float *obj[4] = {nullptr,nullptr,nullptr,nullptr};
  const float *dlt[4] = {nullptr,nullptr,nullptr,nullptr};
  const float *anchors = nullptr;
  for (int i = 0; i < n_in; ++i){
    int s = in_sizes[i];
    const float* p = (const float*)d_in[i];
    switch (s){
      case 786432:  obj[0] = p; break;
      case 4718592: dlt[0] = p; break;
      case 196608:  obj[1] = p; break;
      case 1179648: dlt[1] = p; break;
      case 49152:   obj[2] = p; break;
      case 294912:  dlt[2] = p; break;
      case 12288:   obj[3] = p; break;
      case 73728:   dlt[3] = p; break;
      case 5222400: anchors = p; break;
      default: break;
    }
  }

  char* wsb = (char*)d_ws;
  size_t off = 0;
  auto alloc = [&](size_t bytes)->void*{
    size_t cur = (off + 255) & ~(size_t)255;
    off = cur + bytes;
    return (void*)(wsb + cur);
  };
  int*   cand_j = (int*)  alloc(16*KSEL*sizeof(int));
  float* cscore = (float*)alloc((size_t)NB*NCAND*sizeof(float));
  u32*   csmono = (u32*)  alloc((size_t)NB*NCAND*sizeof(u32));
  u64*   ctb    = (u64*)  alloc((size_t)NB*NCAND*sizeof(u64));
  float* cbox   = (float*)alloc((size_t)NB*NCAND*5*sizeof(float));
  u8*    cvalid = (u8*)   alloc((size_t)NB*NCAND);
  float* sscore = (float*)alloc((size_t)NB*NCAND*sizeof(float));
  float* sbox   = (float*)alloc((size_t)NB*NCAND*5*sizeof(float));
  u8*    svalid = (u8*)   alloc((size_t)NB*NCAND);
  float* geom   = (float*)alloc((size_t)NB*NCAND*16*sizeof(float));
  u64*   maskp  = (u64*)  alloc((size_t)NB*NCAND*32*sizeof(u64));
  u32*   plist  = (u32*)  alloc((size_t)PAIR_CAP*sizeof(u32));
  u32*   pcount = (u32*)  alloc(sizeof(u32));

  hipMemsetAsync(pcount, 0, sizeof(u32), stream);

  hipLaunchKernelGGL(k1_topk, dim3(16), dim3(1024), 0, stream,
                     obj[0], obj[1], obj[2], obj[3], cand_j);
  hipLaunchKernelGGL(k2_decode, dim3(32), dim3(256), 0, stream,
                     obj[0], obj[1], obj[2], obj[3],
                     dlt[0], dlt[1], dlt[2], dlt[3],
                     anchors, cand_j, cscore, csmono, ctb, cbox, cvalid);
  hipLaunchKernelGGL(k3_sort, dim3(4), dim3(1024), 0, stream,
                     csmono, ctb, cscore, cbox, cvalid, sscore, sbox, geom, svalid);
  hipLaunchKernelGGL(k4a_aabb, dim3(65536), dim3(256), 0, stream,
                     geom, maskp, plist, pcount);
  hipLaunchKernelGGL(k4b_clip, dim3(256), dim3(256), 0, stream,
                     geom, plist, pcount, maskp);
  hipLaunchKernelGGL(k5_nms_out, dim3(4), dim3(1024), 0, stream,
                     maskp, svalid, sbox, sscore, (float*)d_out);
}

// Round 8
// 340.244 us; speedup vs baseline: 1.3279x; 1.3279x over previous
//
#include <hip/hip_runtime.h>

typedef unsigned int u32;
typedef unsigned long long u64;
typedef unsigned char u8;

#define NB 4
#define T_ANCH 261120
#define NCAND 2048          // candidates per image (4 levels x 512)
#define KSEL 512
#define POSTN 512
#define LOG_MAXF 4.135166556742356f
#define NMS_TH 0.7f
#define LVL_OFF_F 8192.0f
#define BINS 4096           // top-12 bits of mono32
#define EQCAP 8192          // tie-bin capacity (expected ~300-700 occupants)
#define PAIR_CAP (1u<<20)   // 1M compacted pairs (observed ~17k -> 60x margin)
#define K4A_BLOCKS 1024
#define K4A_PAIRS_PER_BLOCK (NB*NCAND*NCAND/K4A_BLOCKS)   // 16384

__device__ __forceinline__ u32 mono32(float f){
  u32 u = __float_as_uint(f);
  return (u & 0x80000000u) ? ~u : (u | 0x80000000u);
}
__device__ __forceinline__ int lvl_hw(int lvl){ return 65536 >> (2*lvl); }
__device__ __forceinline__ int lvl_off(int lvl){
  return (lvl>0?196608:0) + (lvl>1?49152:0) + (lvl>2?12288:0);
}

// ---------------------------------------------------------------------------
// K1: exact top-512 per (image, level) by key (mono(obj)<<32 | ~j) where j is
// the PERMUTED index (j = pix*3 + a). See R4 notes.
// ---------------------------------------------------------------------------
__global__ __launch_bounds__(1024) void k1_topk(
    const float* __restrict__ o0, const float* __restrict__ o1,
    const float* __restrict__ o2, const float* __restrict__ o3,
    int* __restrict__ cand_j)
{
  int bid = blockIdx.x;
  int b = bid >> 2, lvl = bid & 3;
  const float* ob = (lvl==0)?o0 : (lvl==1)?o1 : (lvl==2)?o2 : o3;
  int hw = lvl_hw(lvl);
  int size = 3*hw;                       // 196608 / 49152 / 12288 / 3072
  const float* base = ob + (size_t)b*size;
  const float4* b4 = (const float4*)base;  // size % 4 == 0, 16B-aligned
  int n4 = size >> 2;

  __shared__ u32 hist[BINS];
  __shared__ u64 eqbuf[EQCAP];
  __shared__ u32 coarse[64];
  __shared__ u32 s_b0, s_cntAbove, s_eqn, s_emit;

  int t = threadIdx.x;

  for (int i = t; i < BINS; i += 1024) hist[i] = 0;
  if (t == 0){ s_eqn = 0; s_emit = 0; }
  __syncthreads();

  // ---- Pass A: histogram of top-12 bits (value-only; order-independent) ----
  for (int i = t; i < n4; i += 1024){
    float4 v = b4[i];
    atomicAdd(&hist[mono32(v.x) >> 20], 1u);
    atomicAdd(&hist[mono32(v.y) >> 20], 1u);
    atomicAdd(&hist[mono32(v.z) >> 20], 1u);
    atomicAdd(&hist[mono32(v.w) >> 20], 1u);
  }
  __syncthreads();

  // ---- Coarse sums, then serial two-level descending walk ----
  if (t < 64){
    u32 s = 0;
    for (int z = 0; z < 64; ++z) s += hist[t*64 + z];
    coarse[t] = s;
  }
  __syncthreads();
  if (t == 0){
    u32 acc = 0;
    int cb = 63;
    while (acc + coarse[cb] < (u32)KSEL){ acc += coarse[cb]; --cb; }
    int z = cb*64 + 63;
    while (acc + hist[z] < (u32)KSEL){ acc += hist[z]; --z; }
    s_b0 = (u32)z;          // bin containing the 512th-largest key
    s_cntAbove = acc;       // count of elements in bins > b0  (< 512)
  }
  __syncthreads();
  u32 b0v = s_b0, cA = s_cntAbove;

  // ---- Pass B: classify (emit PERMUTED index j = (pix+q)*3 + a) ----
  for (int i = t; i < n4; i += 1024){
    float4 v = b4[i];
    int L = i << 2;                 // linear base index (= a*hw + pix)
    int a = L / hw;                 // same for all 4 lanes (hw % 4 == 0)
    int pix = L - a*hw;
    int j0 = pix*3 + a;             // permuted index of element q is j0 + 3q
    u32 m0 = mono32(v.x), m1 = mono32(v.y), m2 = mono32(v.z), m3 = mono32(v.w);
    u32 bb0 = m0 >> 20, bb1 = m1 >> 20, bb2 = m2 >> 20, bb3 = m3 >> 20;
    if (bb0 > b0v){ u32 s = atomicAdd(&s_emit,1u); if (s < (u32)KSEL) cand_j[bid*KSEL+s] = j0; }
    else if (bb0 == b0v){ u32 s = atomicAdd(&s_eqn,1u); if (s < (u32)EQCAP) eqbuf[s] = ((u64)m0<<32) | (u32)(~(u32)j0); }
    if (bb1 > b0v){ u32 s = atomicAdd(&s_emit,1u); if (s < (u32)KSEL) cand_j[bid*KSEL+s] = j0+3; }
    else if (bb1 == b0v){ u32 s = atomicAdd(&s_eqn,1u); if (s < (u32)EQCAP) eqbuf[s] = ((u64)m1<<32) | (u32)(~(u32)(j0+3)); }
    if (bb2 > b0v){ u32 s = atomicAdd(&s_emit,1u); if (s < (u32)KSEL) cand_j[bid*KSEL+s] = j0+6; }
    else if (bb2 == b0v){ u32 s = atomicAdd(&s_eqn,1u); if (s < (u32)EQCAP) eqbuf[s] = ((u64)m2<<32) | (u32)(~(u32)(j0+6)); }
    if (bb3 > b0v){ u32 s = atomicAdd(&s_emit,1u); if (s < (u32)KSEL) cand_j[bid*KSEL+s] = j0+9; }
    else if (bb3 == b0v){ u32 s = atomicAdd(&s_eqn,1u); if (s < (u32)EQCAP) eqbuf[s] = ((u64)m3<<32) | (u32)(~(u32)(j0+9)); }
  }
  __syncthreads();

  // ---- Tie resolution: O(n^2) exact rank-select ----
  u32 n = s_eqn < (u32)EQCAP ? s_eqn : (u32)EQCAP;
  u32 k = (u32)KSEL - cA;                 // >= 1, <= 512
  for (u32 i = t; i < n; i += 1024){
    u64 ki = eqbuf[i];
    u32 r = 0;
    for (u32 mm = 0; mm < n; ++mm) r += (eqbuf[mm] > ki) ? 1u : 0u;
    if (r < k){
      u32 s = atomicAdd(&s_emit, 1u);
      if (s < (u32)KSEL) cand_j[bid*KSEL + s] = (int)(~(u32)ki);
    }
  }
}

// ---------------------------------------------------------------------------
// K2: decode the 8192 selected candidates; build sort keys.
// ---------------------------------------------------------------------------
__global__ __launch_bounds__(256) void k2_decode(
    const float* __restrict__ o0, const float* __restrict__ o1,
    const float* __restrict__ o2, const float* __restrict__ o3,
    const float* __restrict__ d0, const float* __restrict__ d1,
    const float* __restrict__ d2, const float* __restrict__ d3,
    const float* __restrict__ anchors,
    const int* __restrict__ cand_j,
    float* __restrict__ cscore, u32* __restrict__ csmono,
    u64* __restrict__ ctb, float* __restrict__ cbox, u8* __restrict__ cvalid)
{
  int c = blockIdx.x*256 + threadIdx.x;
  if (c >= NB*NCAND) return;
  int pair = c >> 9;          // (b,lvl) pair index
  int b = pair >> 2, lvl = pair & 3;
  int j = cand_j[c];
  int hw = lvl_hw(lvl);
  u32 pix = (u32)j / 3u;
  u32 a = (u32)j - pix*3u;
  const float* ob = (lvl==0)?o0 : (lvl==1)?o1 : (lvl==2)?o2 : o3;
  const float* dl = (lvl==0)?d0 : (lvl==1)?d1 : (lvl==2)?d2 : d3;

  float ov = ob[(size_t)(b*3 + (int)a)*hw + pix];
  size_t dbase = ((size_t)(b*3 + (int)a)*6)*(size_t)hw + pix;
  float dx  = dl[dbase + 0*(size_t)hw];
  float dy  = dl[dbase + 1*(size_t)hw];
  float dw  = dl[dbase + 2*(size_t)hw];
  float dh  = dl[dbase + 3*(size_t)hw];
  float dsn = dl[dbase + 4*(size_t)hw];
  float dcs = dl[dbase + 5*(size_t)hw];
  int tt = lvl_off(lvl) + j;
  const float* an = anchors + ((size_t)b*T_ANCH + tt)*5;
  float ax=an[0], ay=an[1], aw=an[2], ah=an[3], aa=an[4];
  dw = fminf(dw, LOG_MAXF); dh = fminf(dh, LOG_MAXF);
  float cx = ax + dx*aw;
  float cy = ay + dy*ah;
  float w  = aw * expf(dw);
  float h  = ah * expf(dh);
  float ang = aa + atan2f(dsn, dcs);
  double sd = 1.0 / (1.0 + exp(-(double)ov));
  float sc = (float)sd;
  bool valid = (w >= 1e-3f) && (h >= 1e-3f) && (sc >= 0.0f);
  cscore[c] = sc;
  csmono[c] = valid ? mono32(sc) : 0u;        // invalid => -inf (stable-sorted by tb)
  // tiebreak: level asc, obj desc, idx asc  (== reference positional order)
  ctb[c] = ((u64)lvl << 50) | ((u64)(u32)(~mono32(ov)) << 18) | (u64)(u32)j;
  cvalid[c] = valid ? 1 : 0;
  float* bb = cbox + (size_t)c*5;
  bb[0]=cx; bb[1]=cy; bb[2]=w; bb[3]=h; bb[4]=ang;
}

// ---------------------------------------------------------------------------
// K3: per-image stable-equivalent sort (score desc, tb asc) via bitonic in LDS,
// then gather sorted arrays + offset corners / AABB / area geometry.
// ---------------------------------------------------------------------------
__global__ __launch_bounds__(1024) void k3_sort(
    const u32* __restrict__ csmono, const u64* __restrict__ ctb,
    const float* __restrict__ cscore, const float* __restrict__ cbox,
    const u8* __restrict__ cvalid,
    float* __restrict__ sscore, float* __restrict__ sbox,
    float* __restrict__ geom, u8* __restrict__ svalid)
{
  int b = blockIdx.x;
  __shared__ u32 sm[NCAND];
  __shared__ u64 stb[NCAND];
  __shared__ u32 sid[NCAND];
  for (int k = threadIdx.x; k < NCAND; k += 1024){
    sm[k]  = csmono[b*NCAND + k];
    stb[k] = ctb[b*NCAND + k];
    sid[k] = (u32)k;
  }
  __syncthreads();
  for (int kk = 2; kk <= NCAND; kk <<= 1){
    for (int jj = kk >> 1; jj > 0; jj >>= 1){
      for (int i = threadIdx.x; i < NCAND; i += 1024){
        int ixj = i ^ jj;
        if (ixj > i){
          bool dirAsc = ((i & kk) == 0);
          u32 s1 = sm[i], s2 = sm[ixj];
          u64 t1 = stb[i], t2 = stb[ixj];
          bool before_ixj = (s2 > s1) || (s2 == s1 && t2 < t1);
          bool sw = dirAsc ? before_ixj : !before_ixj;
          if (sw){
            sm[i]=s2; sm[ixj]=s1;
            stb[i]=t2; stb[ixj]=t1;
            u32 tmp = sid[i]; sid[i]=sid[ixj]; sid[ixj]=tmp;
          }
        }
      }
      __syncthreads();
    }
  }
  for (int k = threadIdx.x; k < NCAND; k += 1024){
    int id = (int)sid[k];
    int gsrc = b*NCAND + id;
    int gdst = b*NCAND + k;
    float scv = cscore[gsrc];
    sscore[gdst] = scv;
    svalid[gdst] = cvalid[gsrc];
    float b0 = cbox[(size_t)gsrc*5+0], b1 = cbox[(size_t)gsrc*5+1];
    float b2 = cbox[(size_t)gsrc*5+2], b3 = cbox[(size_t)gsrc*5+3];
    float b4 = cbox[(size_t)gsrc*5+4];
    float* sb = sbox + (size_t)gdst*5;
    sb[0]=b0; sb[1]=b1; sb[2]=b2; sb[3]=b3; sb[4]=b4;
    int lvl = (int)((stb[k] >> 50) & 3ull);
    float offv = (float)lvl * LVL_OFF_F;
    float cx = b0 + offv, cy = b1 + offv, w=b2, h=b3, ang=b4;
    float cc = cosf(ang), sn = sinf(ang);
    float hx = 0.5f*w, hy = 0.5f*h;
    float x0 = cx + hx*cc - hy*sn, y0 = cy + hx*sn + hy*cc;
    float x1 = cx - hx*cc - hy*sn, y1 = cy - hx*sn + hy*cc;
    float x2 = cx - hx*cc + hy*sn, y2 = cy - hx*sn - hy*cc;
    float x3 = cx + hx*cc + hy*sn, y3 = cy + hx*sn - hy*cc;
    float minx = fminf(fminf(x0,x1),fminf(x2,x3));
    float maxx = fmaxf(fmaxf(x0,x1),fmaxf(x2,x3));
    float miny = fminf(fminf(y0,y1),fminf(y2,y3));
    float maxy = fmaxf(fmaxf(y0,y1),fmaxf(y2,y3));
    float* g = geom + (size_t)gdst*16;
    g[0]=minx; g[1]=maxx; g[2]=miny; g[3]=maxy; g[4]=w*h;
    g[5]=x0; g[6]=y0; g[7]=x1; g[8]=y1; g[9]=x2; g[10]=y2; g[11]=x3; g[12]=y3;
  }
}

// ---------------------------------------------------------------------------
// K4a: AABB filter -> compacted pair list. 1024 blocks, each owns a
// contiguous 16384-pair range; passes collected in a worst-case-sized LDS
// list (16384 entries, overflow impossible), ONE global atomicAdd per block.
// AABB-disjoint => inter==0 => bit=false (decision-safe reject).
// Mask zeroing is done by hipMemsetAsync before this kernel.
// ---------------------------------------------------------------------------
__global__ __launch_bounds__(256) void k4a_aabb(
    const float* __restrict__ geom,
    u32* __restrict__ list, u32* __restrict__ gcount)
{
  __shared__ u32 lbuf[K4A_PAIRS_PER_BLOCK];   // 64 KB
  __shared__ u32 lcnt, lbase;
  if (threadIdx.x == 0) lcnt = 0;
  __syncthreads();
  u32 base_gt = blockIdx.x * K4A_PAIRS_PER_BLOCK;
  #pragma unroll 4
  for (int it = 0; it < K4A_PAIRS_PER_BLOCK/256; ++it){
    u32 gt = base_gt + (u32)it*256u + threadIdx.x;
    int img = (int)(gt >> 22);
    int rem = (int)(gt & ((1u<<22)-1));
    int i = rem >> 11;
    int j = rem & (NCAND-1);
    bool pass = false;
    if (j > i){
      const float4 gi = *(const float4*)(geom + ((size_t)(img*NCAND + i))*16);
      const float4 gj = *(const float4*)(geom + ((size_t)(img*NCAND + j))*16);
      pass = !(gi.x > gj.y || gj.x > gi.y || gi.z > gj.w || gj.z > gi.w);
    }
    if (pass){
      u32 s = atomicAdd(&lcnt, 1u);
      lbuf[s] = gt;
    }
  }
  __syncthreads();
  if (threadIdx.x == 0) lbase = atomicAdd(gcount, lcnt);
  __syncthreads();
  u32 n = lcnt, bs = lbase;
  for (u32 x = threadIdx.x; x < n; x += 256){
    u32 idx = bs + x;
    if (idx < PAIR_CAP) list[idx] = lbuf[x];
  }
}

// ---------------------------------------------------------------------------
// K4b: dense clip over the compacted list; scatter bits via atomicOr.
// ---------------------------------------------------------------------------
__device__ __forceinline__ void emit_pt(float* ox, float* oy, int oc, float x, float y){
  #pragma unroll
  for (int s = 0; s < 8; ++s) if (s == oc){ ox[s] = x; oy[s] = y; }
}

__device__ float quad_inter(const float* ca, const float* cb){
  float px[8], py[8];
  #pragma unroll
  for (int q = 0; q < 8; ++q){ px[q]=0.f; py[q]=0.f; }
  #pragma unroll
  for (int q = 0; q < 4; ++q){ px[q]=ca[2*q]; py[q]=ca[2*q+1]; }
  int cnt = 4;
  #pragma unroll
  for (int e = 0; e < 4; ++e){
    float p1x = cb[2*e],         p1y = cb[2*e+1];
    float p2x = cb[(2*e+2)&7],   p2y = cb[(2*e+3)&7];
    float ex = p2x-p1x, ey = p2y-p1y;
    float d[8];
    #pragma unroll
    for (int q = 0; q < 8; ++q) d[q] = ex*(py[q]-p1y) - ey*(px[q]-p1x);
    float ox[8], oy[8];
    #pragma unroll
    for (int q = 0; q < 8; ++q){ ox[q]=0.f; oy[q]=0.f; }
    int oc = 0;
    #pragma unroll
    for (int q = 0; q < 8; ++q){
      if (q < cnt){
        bool last = (q+1 >= cnt);
        float dn  = last ? d[0]  : d[(q+1)&7];
        bool in0 = (d[q] >= 0.0f), in1 = (dn >= 0.0f);
        if (in0){ emit_pt(ox,oy,oc,px[q],py[q]); oc++; }
        if (in0 != in1){
          float pnx = last ? px[0] : px[(q+1)&7];
          float pny = last ? py[0] : py[(q+1)&7];
          float den = d[q] - dn;
          float t = d[q] / ((den == 0.0f) ? 1.0f : den);
          emit_pt(ox,oy,oc, px[q] + t*(pnx-px[q]), py[q] + t*(pny-py[q]));
          oc++;
        }
      }
    }
    cnt = (oc > 8) ? 8 : oc;
    #pragma unroll
    for (int q = 0; q < 8; ++q){ px[q]=ox[q]; py[q]=oy[q]; }
  }
  if (cnt < 3) return 0.0f;
  float s = 0.0f;
  #pragma unroll
  for (int q = 0; q < 8; ++q){
    if (q < cnt){
      bool last = (q+1 >= cnt);
      float pnx = last ? px[0] : px[(q+1)&7];
      float pny = last ? py[0] : py[(q+1)&7];
      s += px[q]*pny - pnx*py[q];
    }
  }
  return 0.5f*fabsf(s);
}

__global__ __launch_bounds__(256) void k4b_clip(
    const float* __restrict__ geom, const u32* __restrict__ list,
    const u32* __restrict__ gcount, u64* __restrict__ mask)
{
  u32 count = *gcount;
  if (count > PAIR_CAP) count = PAIR_CAP;
  for (u32 idx = blockIdx.x*256 + threadIdx.x; idx < count; idx += gridDim.x*256){
    u32 gt = list[idx];
    int img = (int)(gt >> 22);
    int rem = (int)(gt & ((1u<<22)-1));
    int i = rem >> 11;
    int j = rem & (NCAND-1);
    const float* gi = geom + ((size_t)(img*NCAND + i))*16;
    const float* gj = geom + ((size_t)(img*NCAND + j))*16;
    float inter = quad_inter(gi+5, gj+5);
    float iou = inter / (gi[4] + gj[4] - inter + 1e-7f);
    if (iou > NMS_TH)
      atomicOr(&mask[((size_t)(img*NCAND + i))*32 + (j >> 6)], 1ull << (j & 63));
  }
}

// ---------------------------------------------------------------------------
// K5: sequential greedy suppression, sup in wave-0 registers, early exit at
// the 512th kept row (see R6 notes).
// ---------------------------------------------------------------------------
__global__ __launch_bounds__(1024) void k5_nms_out(
    const u64* __restrict__ mask, const u8* __restrict__ svalid,
    const float* __restrict__ sbox, const float* __restrict__ sscore,
    float* __restrict__ out)
{
  int b = blockIdx.x;
  __shared__ u64 buf[2][128*32];      // 64 KB double buffer
  __shared__ u64 s_kept[32];
  __shared__ u32 pref[32];
  __shared__ u32 s_done, s_R;
  int t = threadIdx.x;
  int wid = t >> 6, lane = t & 63;

  if (t == 0){ s_done = 0; s_R = NCAND - 1; }

  // sup init from svalid: lane l (l<32) builds word l; lanes 32-63 mirror.
  u32 slo = 0, shi = 0;
  if (wid == 0){
    int wl = lane & 31;
    u64 w = 0;
    for (int q = 0; q < 64; ++q)
      if (!svalid[b*NCAND + wl*64 + q]) w |= (1ull << q);
    slo = (u32)w; shi = (u32)(w >> 32);
  }
  // preload chunk 0 (all waves)
  {
    const u64* src = mask + ((size_t)b*NCAND)*32;
    for (int x = t; x < 128*32; x += 1024) buf[0][x] = src[x];
  }
  __syncthreads();

  u32 kcnt = 0;
  bool stopped = false;
  for (int c = 0; c < 16; ++c){
    if (wid != 0){
      if (c + 1 < 16){
        const u64* src = mask + ((size_t)(b*NCAND + (c+1)*128))*32;
        for (int x = t - 64; x < 128*32; x += (1024 - 64))
          buf[(c+1)&1][x] = src[x];
      }
    } else if (!stopped){
      const u64* ch = buf[c&1];
      for (int r8 = 0; r8 < 128 && !stopped; r8 += 8){
        u64 v[8];
        #pragma unroll
        for (int q = 0; q < 8; ++q) v[q] = ch[(r8+q)*32 + (lane & 31)];
        #pragma unroll
        for (int q = 0; q < 8; ++q){
          int gi = c*128 + r8 + q;
          int wi = gi >> 6;                       // wave-uniform
          u32 wlo = (u32)__builtin_amdgcn_readlane((int)slo, wi);
          u32 whi = (u32)__builtin_amdgcn_readlane((int)shi, wi);
          u64 w = ((u64)whi << 32) | wlo;
          u32 keep = (u32)((~w >> (gi & 63)) & 1ull);
          u64 vm = v[q] & (0ull - (u64)keep);     // branchless: keep ? v : 0
          slo |= (u32)vm; shi |= (u32)(vm >> 32);
          kcnt += keep;
          if (kcnt >= (u32)POSTN){                // 512th keep -> stop
            if (lane == 0){ s_done = 1; s_R = (u32)gi; }
            stopped = true;
            break;
          }
        }
      }
    }
    __syncthreads();
    if (s_done) break;
    __syncthreads();
  }
  // publish kept words, range-masked to rows <= R
  if (wid == 0 && lane < 32){
    u32 Rv = s_R;
    int lo_row = (int)lane * 64;
    u64 sup = ((u64)shi << 32) | slo;
    u64 rmask;
    if (lo_row + 63 <= (int)Rv) rmask = ~0ull;
    else if (lo_row > (int)Rv)  rmask = 0ull;
    else                        rmask = (1ull << ((int)Rv - lo_row + 1)) - 1ull;
    s_kept[lane] = (~sup) & rmask;
  }
  __syncthreads();

  // zero-fill this image's output (d_out is poisoned before every launch)
  for (int x = t; x < POSTN*5; x += 1024) out[(size_t)b*POSTN*5 + x] = 0.0f;
  for (int x = t; x < POSTN;   x += 1024) out[(size_t)NB*POSTN*5 + b*POSTN + x] = 0.0f;
  if (t < 32) pref[t] = (u32)__popcll(s_kept[t]);
  __syncthreads();
  if (t == 0){
    u32 run = 0;
    for (int w = 0; w < 32; ++w){ u32 tv = pref[w]; pref[w] = run; run += tv; }
  }
  __syncthreads();
  for (int i = t; i < NCAND; i += 1024){
    u64 kw = s_kept[i >> 6];
    if ((kw >> (i & 63)) & 1ull){
      u32 rank = pref[i >> 6] + (u32)__popcll(kw & ((1ull << (i & 63)) - 1ull));
      if (rank < POSTN){
        const float* bp = sbox + ((size_t)(b*NCAND + i))*5;
        float* op = out + ((size_t)(b*POSTN + rank))*5;
        op[0]=bp[0]; op[1]=bp[1]; op[2]=bp[2]; op[3]=bp[3]; op[4]=bp[4];
        out[(size_t)NB*POSTN*5 + b*POSTN + rank] = sscore[b*NCAND + i];
      }
    }
  }
}

// ---------------------------------------------------------------------------
extern "C" void kernel_launch(void* const* d_in, const int* in_sizes, int n_in,
                              void* d_out, int out_size, void* d_ws, size_t ws_size,
                              hipStream_t stream)
{
  (void)out_size; (void)ws_size;
  const float *obj[4] = {nullptr,nullptr,nullptr,nullptr};
  const float *dlt[4] = {nullptr,nullptr,nullptr,nullptr};
  const float *anchors = nullptr;
  for (int i = 0; i < n_in; ++i){
    int s = in_sizes[i];
    const float* p = (const float*)d_in[i];
    switch (s){
      case 786432:  obj[0] = p; break;
      case 4718592: dlt[0] = p; break;
      case 196608:  obj[1] = p; break;
      case 1179648: dlt[1] = p; break;
      case 49152:   obj[2] = p; break;
      case 294912:  dlt[2] = p; break;
      case 12288:   obj[3] = p; break;
      case 73728:   dlt[3] = p; break;
      case 5222400: anchors = p; break;
      default: break;
    }
  }

  char* wsb = (char*)d_ws;
  size_t off = 0;
  auto alloc = [&](size_t bytes)->void*{
    size_t cur = (off + 255) & ~(size_t)255;
    off = cur + bytes;
    return (void*)(wsb + cur);
  };
  int*   cand_j = (int*)  alloc(16*KSEL*sizeof(int));
  float* cscore = (float*)alloc((size_t)NB*NCAND*sizeof(float));
  u32*   csmono = (u32*)  alloc((size_t)NB*NCAND*sizeof(u32));
  u64*   ctb    = (u64*)  alloc((size_t)NB*NCAND*sizeof(u64));
  float* cbox   = (float*)alloc((size_t)NB*NCAND*5*sizeof(float));
  u8*    cvalid = (u8*)   alloc((size_t)NB*NCAND);
  float* sscore = (float*)alloc((size_t)NB*NCAND*sizeof(float));
  float* sbox   = (float*)alloc((size_t)NB*NCAND*5*sizeof(float));
  u8*    svalid = (u8*)   alloc((size_t)NB*NCAND);
  float* geom   = (float*)alloc((size_t)NB*NCAND*16*sizeof(float));
  u64*   maskp  = (u64*)  alloc((size_t)NB*NCAND*32*sizeof(u64));
  u32*   plist  = (u32*)  alloc((size_t)PAIR_CAP*sizeof(u32));
  u32*   pcount = (u32*)  alloc(sizeof(u32));

  hipMemsetAsync(pcount, 0, sizeof(u32), stream);
  hipMemsetAsync(maskp, 0, (size_t)NB*NCAND*32*sizeof(u64), stream);

  hipLaunchKernelGGL(k1_topk, dim3(16), dim3(1024), 0, stream,
                     obj[0], obj[1], obj[2], obj[3], cand_j);
  hipLaunchKernelGGL(k2_decode, dim3(32), dim3(256), 0, stream,
                     obj[0], obj[1], obj[2], obj[3],
                     dlt[0], dlt[1], dlt[2], dlt[3],
                     anchors, cand_j, cscore, csmono, ctb, cbox, cvalid);
  hipLaunchKernelGGL(k3_sort, dim3(4), dim3(1024), 0, stream,
                     csmono, ctb, cscore, cbox, cvalid, sscore, sbox, geom, svalid);
  hipLaunchKernelGGL(k4a_aabb, dim3(K4A_BLOCKS), dim3(256), 0, stream,
                     geom, plist, pcount);
  hipLaunchKernelGGL(k4b_clip, dim3(256), dim3(256), 0, stream,
                     geom, plist, pcount, maskp);
  hipLaunchKernelGGL(k5_nms_out, dim3(4), dim3(1024), 0, stream,
                     maskp, svalid, sbox, sscore, (float*)d_out);
}

// Round 9
// 307.707 us; speedup vs baseline: 1.4683x; 1.1057x over previous
//
#include <hip/hip_runtime.h>

typedef unsigned int u32;
typedef unsigned long long u64;
typedef unsigned char u8;

#define NB 4
#define T_ANCH 261120
#define NCAND 2048          // candidates per image (4 levels x 512)
#define KSEL 512
#define POSTN 512
#define LOG_MAXF 4.135166556742356f
#define NMS_TH 0.7f
#define LVL_OFF_F 8192.0f
#define BINS 4096           // top-12 bits of mono32
#define EQCAP 8192          // tie-bin capacity (expected ~300-700 occupants)
#define PAIR_CAP (1u<<20)   // 1M compacted pairs
#define K4A_BLOCKS 1024
#define K4A_PAIRS_PER_BLOCK (NB*NCAND*NCAND/K4A_BLOCKS)   // 16384
#define K1_BLOCKS 256       // 64 chunk-blocks per image (48/12/3/1 per level)

__device__ __forceinline__ u32 mono32(float f){
  u32 u = __float_as_uint(f);
  return (u & 0x80000000u) ? ~u : (u | 0x80000000u);
}
__device__ __forceinline__ int lvl_hw(int lvl){ return 65536 >> (2*lvl); }
__device__ __forceinline__ int lvl_off(int lvl){
  return (lvl>0?196608:0) + (lvl>1?49152:0) + (lvl>2?12288:0);
}
// chunk-block mapping: bx in [0,256): b = bx>>6, c = bx&63
// c<48 -> lvl0 chunk c ; c<60 -> lvl1 chunk c-48 ; c<63 -> lvl2 chunk c-60 ; else lvl3
__device__ __forceinline__ void k1_map(int bx, int& b, int& lvl, int& ch){
  b = bx >> 6;
  int c = bx & 63;
  if (c < 48){ lvl = 0; ch = c; }
  else if (c < 60){ lvl = 1; ch = c - 48; }
  else if (c < 63){ lvl = 2; ch = c - 60; }
  else { lvl = 3; ch = 0; }
}

// ---------------------------------------------------------------------------
// K1a: per-chunk private histogram of mono32>>20. 256 blocks, 1 float4/thread.
// Full 4096-bin overwrite -> no global zeroing/atomics needed.
// ---------------------------------------------------------------------------
__global__ __launch_bounds__(1024) void k1a_hist(
    const float* __restrict__ o0, const float* __restrict__ o1,
    const float* __restrict__ o2, const float* __restrict__ o3,
    u32* __restrict__ ghist)
{
  int b, lvl, ch;
  k1_map(blockIdx.x, b, lvl, ch);
  const float* ob = (lvl==0)?o0 : (lvl==1)?o1 : (lvl==2)?o2 : o3;
  int hw = lvl_hw(lvl);
  int size = 3*hw;
  int n4 = size >> 2;
  int i4 = ch*1024 + threadIdx.x;
  __shared__ u32 hist[BINS];
  for (int i = threadIdx.x; i < BINS; i += 1024) hist[i] = 0;
  __syncthreads();
  if (i4 < n4){
    float4 v = ((const float4*)(ob + (size_t)b*size))[i4];
    atomicAdd(&hist[mono32(v.x) >> 20], 1u);
    atomicAdd(&hist[mono32(v.y) >> 20], 1u);
    atomicAdd(&hist[mono32(v.z) >> 20], 1u);
    atomicAdd(&hist[mono32(v.w) >> 20], 1u);
  }
  __syncthreads();
  u32* out = ghist + (size_t)blockIdx.x*BINS;
  for (int i = threadIdx.x; i < BINS; i += 1024) out[i] = hist[i];
}

// ---------------------------------------------------------------------------
// K1b: reduce chunk histograms per (b,lvl); serial threshold walk -> b0,
// cntAbove; zero emit/tie counters.
// ---------------------------------------------------------------------------
__global__ __launch_bounds__(1024) void k1b_thresh(
    const u32* __restrict__ ghist, u32* __restrict__ gb0,
    u32* __restrict__ gcA, u32* __restrict__ emitcnt, u32* __restrict__ tiecnt)
{
  int bid = blockIdx.x;               // 16 = (b,lvl)
  int b = bid >> 2, lvl = bid & 3;
  int base_bx = b*64 + (lvl==0?0 : lvl==1?48 : lvl==2?60 : 63);
  int nch = (lvl==0?48 : lvl==1?12 : lvl==2?3 : 1);
  __shared__ u32 hist[BINS];
  __shared__ u32 coarse[64];
  int t = threadIdx.x;
  u32 c0=0,c1=0,c2=0,c3=0;
  for (int ch = 0; ch < nch; ++ch){
    const u32* h = ghist + (size_t)(base_bx+ch)*BINS;
    c0 += h[4*t+0]; c1 += h[4*t+1]; c2 += h[4*t+2]; c3 += h[4*t+3];
  }
  hist[4*t+0]=c0; hist[4*t+1]=c1; hist[4*t+2]=c2; hist[4*t+3]=c3;
  __syncthreads();
  if (t < 64){
    u32 s = 0;
    for (int z = 0; z < 64; ++z) s += hist[t*64 + z];
    coarse[t] = s;
  }
  __syncthreads();
  if (t == 0){
    u32 acc = 0;
    int cb = 63;
    while (acc + coarse[cb] < (u32)KSEL){ acc += coarse[cb]; --cb; }
    int z = cb*64 + 63;
    while (acc + hist[z] < (u32)KSEL){ acc += hist[z]; --z; }
    gb0[bid] = (u32)z;
    gcA[bid] = acc;
    emitcnt[bid] = 0;
    tiecnt[bid] = 0;
  }
}

// ---------------------------------------------------------------------------
// K1c: classify chunk elements vs b0. LDS lists + ONE global reservation per
// list per block. Emits PERMUTED index j = pix*3 + a (see R4 notes).
// ---------------------------------------------------------------------------
__global__ __launch_bounds__(1024) void k1c_classify(
    const float* __restrict__ o0, const float* __restrict__ o1,
    const float* __restrict__ o2, const float* __restrict__ o3,
    const u32* __restrict__ gb0,
    u32* __restrict__ emitcnt, u32* __restrict__ tiecnt,
    int* __restrict__ cand_j, u64* __restrict__ gtie)
{
  int b, lvl, ch;
  k1_map(blockIdx.x, b, lvl, ch);
  int bid16 = b*4 + lvl;
  const float* ob = (lvl==0)?o0 : (lvl==1)?o1 : (lvl==2)?o2 : o3;
  int hw = lvl_hw(lvl);
  int size = 3*hw;
  int n4 = size >> 2;
  int i4 = ch*1024 + threadIdx.x;

  __shared__ u32 dbuf[KSEL];
  __shared__ u64 tbuf[4096];
  __shared__ u32 dn, tn, dbase, tbase;
  if (threadIdx.x == 0){ dn = 0; tn = 0; }
  __syncthreads();

  u32 b0v = gb0[bid16];
  if (i4 < n4){
    float4 v = ((const float4*)(ob + (size_t)b*size))[i4];
    int L = i4 << 2;
    int a = L / hw;                 // hw % 4 == 0 -> same a for all 4
    int pix = L - a*hw;
    int j0 = pix*3 + a;
    float vv[4] = {v.x, v.y, v.z, v.w};
    #pragma unroll
    for (int q = 0; q < 4; ++q){
      u32 m = mono32(vv[q]);
      u32 bin = m >> 20;
      int j = j0 + 3*q;
      if (bin > b0v){
        u32 s = atomicAdd(&dn, 1u);
        if (s < (u32)KSEL) dbuf[s] = (u32)j;
      } else if (bin == b0v){
        u32 s = atomicAdd(&tn, 1u);
        if (s < 4096u) tbuf[s] = ((u64)m << 32) | (u32)(~(u32)j);
      }
    }
  }
  __syncthreads();
  if (threadIdx.x == 0){
    dbase = dn ? atomicAdd(&emitcnt[bid16], dn) : 0u;
    tbase = tn ? atomicAdd(&tiecnt[bid16], tn) : 0u;
  }
  __syncthreads();
  for (u32 x = threadIdx.x; x < dn; x += 1024){
    u32 s = dbase + x;
    if (s < (u32)KSEL) cand_j[bid16*KSEL + s] = (int)dbuf[x];
  }
  for (u32 x = threadIdx.x; x < tn; x += 1024){
    u32 s = tbase + x;
    if (s < (u32)EQCAP) gtie[(size_t)bid16*EQCAP + s] = tbuf[x];
  }
}

// ---------------------------------------------------------------------------
// K1d: O(n^2) exact rank-select on the tie set; append k = 512-cntAbove
// winners (LDS-aggregated, one global reservation).
// ---------------------------------------------------------------------------
__global__ __launch_bounds__(1024) void k1d_tie(
    const u64* __restrict__ gtie, const u32* __restrict__ tiecnt,
    const u32* __restrict__ gcA, u32* __restrict__ emitcnt,
    int* __restrict__ cand_j)
{
  int bid = blockIdx.x;               // 16
  __shared__ u64 eq[EQCAP];           // 64 KB
  __shared__ u32 wbuf[KSEL];
  __shared__ u32 wn, wbase;
  u32 n = tiecnt[bid]; if (n > (u32)EQCAP) n = (u32)EQCAP;
  u32 k = (u32)KSEL - gcA[bid];
  if (threadIdx.x == 0) wn = 0;
  for (u32 i = threadIdx.x; i < n; i += 1024) eq[i] = gtie[(size_t)bid*EQCAP + i];
  __syncthreads();
  for (u32 i = threadIdx.x; i < n; i += 1024){
    u64 ki = eq[i];
    u32 r = 0;
    for (u32 m = 0; m < n; ++m) r += (eq[m] > ki) ? 1u : 0u;
    if (r < k){
      u32 s = atomicAdd(&wn, 1u);
      if (s < (u32)KSEL) wbuf[s] = (u32)(~(u32)ki);
    }
  }
  __syncthreads();
  if (threadIdx.x == 0) wbase = wn ? atomicAdd(&emitcnt[bid], wn) : 0u;
  __syncthreads();
  for (u32 x = threadIdx.x; x < wn; x += 1024){
    u32 s = wbase + x;
    if (s < (u32)KSEL) cand_j[bid*KSEL + s] = (int)wbuf[x];
  }
}

// ---------------------------------------------------------------------------
// K2: decode the 8192 selected candidates; build sort keys.
// ---------------------------------------------------------------------------
__global__ __launch_bounds__(256) void k2_decode(
    const float* __restrict__ o0, const float* __restrict__ o1,
    const float* __restrict__ o2, const float* __restrict__ o3,
    const float* __restrict__ d0, const float* __restrict__ d1,
    const float* __restrict__ d2, const float* __restrict__ d3,
    const float* __restrict__ anchors,
    const int* __restrict__ cand_j,
    float* __restrict__ cscore, u32* __restrict__ csmono,
    u64* __restrict__ ctb, float* __restrict__ cbox, u8* __restrict__ cvalid)
{
  int c = blockIdx.x*256 + threadIdx.x;
  if (c >= NB*NCAND) return;
  int pair = c >> 9;          // (b,lvl) pair index
  int b = pair >> 2, lvl = pair & 3;
  int j = cand_j[c];
  int hw = lvl_hw(lvl);
  u32 pix = (u32)j / 3u;
  u32 a = (u32)j - pix*3u;
  const float* ob = (lvl==0)?o0 : (lvl==1)?o1 : (lvl==2)?o2 : o3;
  const float* dl = (lvl==0)?d0 : (lvl==1)?d1 : (lvl==2)?d2 : d3;

  float ov = ob[(size_t)(b*3 + (int)a)*hw + pix];
  size_t dbase = ((size_t)(b*3 + (int)a)*6)*(size_t)hw + pix;
  float dx  = dl[dbase + 0*(size_t)hw];
  float dy  = dl[dbase + 1*(size_t)hw];
  float dw  = dl[dbase + 2*(size_t)hw];
  float dh  = dl[dbase + 3*(size_t)hw];
  float dsn = dl[dbase + 4*(size_t)hw];
  float dcs = dl[dbase + 5*(size_t)hw];
  int tt = lvl_off(lvl) + j;
  const float* an = anchors + ((size_t)b*T_ANCH + tt)*5;
  float ax=an[0], ay=an[1], aw=an[2], ah=an[3], aa=an[4];
  dw = fminf(dw, LOG_MAXF); dh = fminf(dh, LOG_MAXF);
  float cx = ax + dx*aw;
  float cy = ay + dy*ah;
  float w  = aw * expf(dw);
  float h  = ah * expf(dh);
  float ang = aa + atan2f(dsn, dcs);
  double sd = 1.0 / (1.0 + exp(-(double)ov));
  float sc = (float)sd;
  bool valid = (w >= 1e-3f) && (h >= 1e-3f) && (sc >= 0.0f);
  cscore[c] = sc;
  csmono[c] = valid ? mono32(sc) : 0u;        // invalid => -inf (stable-sorted by tb)
  // tiebreak: level asc, obj desc, idx asc  (== reference positional order)
  ctb[c] = ((u64)lvl << 50) | ((u64)(u32)(~mono32(ov)) << 18) | (u64)(u32)j;
  cvalid[c] = valid ? 1 : 0;
  float* bb = cbox + (size_t)c*5;
  bb[0]=cx; bb[1]=cy; bb[2]=w; bb[3]=h; bb[4]=ang;
}

// ---------------------------------------------------------------------------
// K3: per-image stable-equivalent sort (score desc, tb asc) via bitonic in LDS,
// then gather sorted arrays + offset corners / AABB / area geometry.
// ---------------------------------------------------------------------------
__global__ __launch_bounds__(1024) void k3_sort(
    const u32* __restrict__ csmono, const u64* __restrict__ ctb,
    const float* __restrict__ cscore, const float* __restrict__ cbox,
    const u8* __restrict__ cvalid,
    float* __restrict__ sscore, float* __restrict__ sbox,
    float* __restrict__ geom, u8* __restrict__ svalid)
{
  int b = blockIdx.x;
  __shared__ u32 sm[NCAND];
  __shared__ u64 stb[NCAND];
  __shared__ u32 sid[NCAND];
  for (int k = threadIdx.x; k < NCAND; k += 1024){
    sm[k]  = csmono[b*NCAND + k];
    stb[k] = ctb[b*NCAND + k];
    sid[k] = (u32)k;
  }
  __syncthreads();
  for (int kk = 2; kk <= NCAND; kk <<= 1){
    for (int jj = kk >> 1; jj > 0; jj >>= 1){
      for (int i = threadIdx.x; i < NCAND; i += 1024){
        int ixj = i ^ jj;
        if (ixj > i){
          bool dirAsc = ((i & kk) == 0);
          u32 s1 = sm[i], s2 = sm[ixj];
          u64 t1 = stb[i], t2 = stb[ixj];
          bool before_ixj = (s2 > s1) || (s2 == s1 && t2 < t1);
          bool sw = dirAsc ? before_ixj : !before_ixj;
          if (sw){
            sm[i]=s2; sm[ixj]=s1;
            stb[i]=t2; stb[ixj]=t1;
            u32 tmp = sid[i]; sid[i]=sid[ixj]; sid[ixj]=tmp;
          }
        }
      }
      __syncthreads();
    }
  }
  for (int k = threadIdx.x; k < NCAND; k += 1024){
    int id = (int)sid[k];
    int gsrc = b*NCAND + id;
    int gdst = b*NCAND + k;
    float scv = cscore[gsrc];
    sscore[gdst] = scv;
    svalid[gdst] = cvalid[gsrc];
    float b0 = cbox[(size_t)gsrc*5+0], b1 = cbox[(size_t)gsrc*5+1];
    float b2 = cbox[(size_t)gsrc*5+2], b3 = cbox[(size_t)gsrc*5+3];
    float b4 = cbox[(size_t)gsrc*5+4];
    float* sb = sbox + (size_t)gdst*5;
    sb[0]=b0; sb[1]=b1; sb[2]=b2; sb[3]=b3; sb[4]=b4;
    int lvl = (int)((stb[k] >> 50) & 3ull);
    float offv = (float)lvl * LVL_OFF_F;
    float cx = b0 + offv, cy = b1 + offv, w=b2, h=b3, ang=b4;
    float cc = cosf(ang), sn = sinf(ang);
    float hx = 0.5f*w, hy = 0.5f*h;
    float x0 = cx + hx*cc - hy*sn, y0 = cy + hx*sn + hy*cc;
    float x1 = cx - hx*cc - hy*sn, y1 = cy - hx*sn + hy*cc;
    float x2 = cx - hx*cc + hy*sn, y2 = cy - hx*sn - hy*cc;
    float x3 = cx + hx*cc + hy*sn, y3 = cy + hx*sn - hy*cc;
    float minx = fminf(fminf(x0,x1),fminf(x2,x3));
    float maxx = fmaxf(fmaxf(x0,x1),fmaxf(x2,x3));
    float miny = fminf(fminf(y0,y1),fminf(y2,y3));
    float maxy = fmaxf(fmaxf(y0,y1),fmaxf(y2,y3));
    float* g = geom + (size_t)gdst*16;
    g[0]=minx; g[1]=maxx; g[2]=miny; g[3]=maxy; g[4]=w*h;
    g[5]=x0; g[6]=y0; g[7]=x1; g[8]=y1; g[9]=x2; g[10]=y2; g[11]=x3; g[12]=y3;
  }
}

// ---------------------------------------------------------------------------
// K4a: AABB filter -> compacted pair list (worst-case LDS list, one global
// atomic per block). See R8 notes.
// ---------------------------------------------------------------------------
__global__ __launch_bounds__(256) void k4a_aabb(
    const float* __restrict__ geom,
    u32* __restrict__ list, u32* __restrict__ gcount)
{
  __shared__ u32 lbuf[K4A_PAIRS_PER_BLOCK];   // 64 KB
  __shared__ u32 lcnt, lbase;
  if (threadIdx.x == 0) lcnt = 0;
  __syncthreads();
  u32 base_gt = blockIdx.x * K4A_PAIRS_PER_BLOCK;
  #pragma unroll 4
  for (int it = 0; it < K4A_PAIRS_PER_BLOCK/256; ++it){
    u32 gt = base_gt + (u32)it*256u + threadIdx.x;
    int img = (int)(gt >> 22);
    int rem = (int)(gt & ((1u<<22)-1));
    int i = rem >> 11;
    int j = rem & (NCAND-1);
    bool pass = false;
    if (j > i){
      const float4 gi = *(const float4*)(geom + ((size_t)(img*NCAND + i))*16);
      const float4 gj = *(const float4*)(geom + ((size_t)(img*NCAND + j))*16);
      pass = !(gi.x > gj.y || gj.x > gi.y || gi.z > gj.w || gj.z > gi.w);
    }
    if (pass){
      u32 s = atomicAdd(&lcnt, 1u);
      lbuf[s] = gt;
    }
  }
  __syncthreads();
  if (threadIdx.x == 0) lbase = atomicAdd(gcount, lcnt);
  __syncthreads();
  u32 n = lcnt, bs = lbase;
  for (u32 x = threadIdx.x; x < n; x += 256){
    u32 idx = bs + x;
    if (idx < PAIR_CAP) list[idx] = lbuf[x];
  }
}

// ---------------------------------------------------------------------------
// K4b: dense clip over the compacted list; scatter bits via atomicOr.
// ---------------------------------------------------------------------------
__device__ __forceinline__ void emit_pt(float* ox, float* oy, int oc, float x, float y){
  #pragma unroll
  for (int s = 0; s < 8; ++s) if (s == oc){ ox[s] = x; oy[s] = y; }
}

__device__ float quad_inter(const float* ca, const float* cb){
  float px[8], py[8];
  #pragma unroll
  for (int q = 0; q < 8; ++q){ px[q]=0.f; py[q]=0.f; }
  #pragma unroll
  for (int q = 0; q < 4; ++q){ px[q]=ca[2*q]; py[q]=ca[2*q+1]; }
  int cnt = 4;
  #pragma unroll
  for (int e = 0; e < 4; ++e){
    float p1x = cb[2*e],         p1y = cb[2*e+1];
    float p2x = cb[(2*e+2)&7],   p2y = cb[(2*e+3)&7];
    float ex = p2x-p1x, ey = p2y-p1y;
    float d[8];
    #pragma unroll
    for (int q = 0; q < 8; ++q) d[q] = ex*(py[q]-p1y) - ey*(px[q]-p1x);
    float ox[8], oy[8];
    #pragma unroll
    for (int q = 0; q < 8; ++q){ ox[q]=0.f; oy[q]=0.f; }
    int oc = 0;
    #pragma unroll
    for (int q = 0; q < 8; ++q){
      if (q < cnt){
        bool last = (q+1 >= cnt);
        float dn  = last ? d[0]  : d[(q+1)&7];
        bool in0 = (d[q] >= 0.0f), in1 = (dn >= 0.0f);
        if (in0){ emit_pt(ox,oy,oc,px[q],py[q]); oc++; }
        if (in0 != in1){
          float pnx = last ? px[0] : px[(q+1)&7];
          float pny = last ? py[0] : py[(q+1)&7];
          float den = d[q] - dn;
          float t = d[q] / ((den == 0.0f) ? 1.0f : den);
          emit_pt(ox,oy,oc, px[q] + t*(pnx-px[q]), py[q] + t*(pny-py[q]));
          oc++;
        }
      }
    }
    cnt = (oc > 8) ? 8 : oc;
    #pragma unroll
    for (int q = 0; q < 8; ++q){ px[q]=ox[q]; py[q]=oy[q]; }
  }
  if (cnt < 3) return 0.0f;
  float s = 0.0f;
  #pragma unroll
  for (int q = 0; q < 8; ++q){
    if (q < cnt){
      bool last = (q+1 >= cnt);
      float pnx = last ? px[0] : px[(q+1)&7];
      float pny = last ? py[0] : py[(q+1)&7];
      s += px[q]*pny - pnx*py[q];
    }
  }
  return 0.5f*fabsf(s);
}

__global__ __launch_bounds__(256) void k4b_clip(
    const float* __restrict__ geom, const u32* __restrict__ list,
    const u32* __restrict__ gcount, u64* __restrict__ mask)
{
  u32 count = *gcount;
  if (count > PAIR_CAP) count = PAIR_CAP;
  for (u32 idx = blockIdx.x*256 + threadIdx.x; idx < count; idx += gridDim.x*256){
    u32 gt = list[idx];
    int img = (int)(gt >> 22);
    int rem = (int)(gt & ((1u<<22)-1));
    int i = rem >> 11;
    int j = rem & (NCAND-1);
    const float* gi = geom + ((size_t)(img*NCAND + i))*16;
    const float* gj = geom + ((size_t)(img*NCAND + j))*16;
    float inter = quad_inter(gi+5, gj+5);
    float iou = inter / (gi[4] + gj[4] - inter + 1e-7f);
    if (iou > NMS_TH)
      atomicOr(&mask[((size_t)(img*NCAND + i))*32 + (j >> 6)], 1ull << (j & 63));
  }
}

// ---------------------------------------------------------------------------
// K5: sequential greedy suppression, sup in wave-0 registers, early exit at
// the 512th kept row (see R6 notes).
// ---------------------------------------------------------------------------
__global__ __launch_bounds__(1024) void k5_nms_out(
    const u64* __restrict__ mask, const u8* __restrict__ svalid,
    const float* __restrict__ sbox, const float* __restrict__ sscore,
    float* __restrict__ out)
{
  int b = blockIdx.x;
  __shared__ u64 buf[2][128*32];      // 64 KB double buffer
  __shared__ u64 s_kept[32];
  __shared__ u32 pref[32];
  __shared__ u32 s_done, s_R;
  int t = threadIdx.x;
  int wid = t >> 6, lane = t & 63;

  if (t == 0){ s_done = 0; s_R = NCAND - 1; }

  // sup init from svalid: lane l (l<32) builds word l; lanes 32-63 mirror.
  u32 slo = 0, shi = 0;
  if (wid == 0){
    int wl = lane & 31;
    u64 w = 0;
    for (int q = 0; q < 64; ++q)
      if (!svalid[b*NCAND + wl*64 + q]) w |= (1ull << q);
    slo = (u32)w; shi = (u32)(w >> 32);
  }
  // preload chunk 0 (all waves)
  {
    const u64* src = mask + ((size_t)b*NCAND)*32;
    for (int x = t; x < 128*32; x += 1024) buf[0][x] = src[x];
  }
  __syncthreads();

  u32 kcnt = 0;
  bool stopped = false;
  for (int c = 0; c < 16; ++c){
    if (wid != 0){
      if (c + 1 < 16){
        const u64* src = mask + ((size_t)(b*NCAND + (c+1)*128))*32;
        for (int x = t - 64; x < 128*32; x += (1024 - 64))
          buf[(c+1)&1][x] = src[x];
      }
    } else if (!stopped){
      const u64* ch = buf[c&1];
      for (int r8 = 0; r8 < 128 && !stopped; r8 += 8){
        u64 v[8];
        #pragma unroll
        for (int q = 0; q < 8; ++q) v[q] = ch[(r8+q)*32 + (lane & 31)];
        #pragma unroll
        for (int q = 0; q < 8; ++q){
          int gi = c*128 + r8 + q;
          int wi = gi >> 6;                       // wave-uniform
          u32 wlo = (u32)__builtin_amdgcn_readlane((int)slo, wi);
          u32 whi = (u32)__builtin_amdgcn_readlane((int)shi, wi);
          u64 w = ((u64)whi << 32) | wlo;
          u32 keep = (u32)((~w >> (gi & 63)) & 1ull);
          u64 vm = v[q] & (0ull - (u64)keep);     // branchless: keep ? v : 0
          slo |= (u32)vm; shi |= (u32)(vm >> 32);
          kcnt += keep;
          if (kcnt >= (u32)POSTN){                // 512th keep -> stop
            if (lane == 0){ s_done = 1; s_R = (u32)gi; }
            stopped = true;
            break;
          }
        }
      }
    }
    __syncthreads();
    if (s_done) break;
    __syncthreads();
  }
  // publish kept words, range-masked to rows <= R
  if (wid == 0 && lane < 32){
    u32 Rv = s_R;
    int lo_row = (int)lane * 64;
    u64 sup = ((u64)shi << 32) | slo;
    u64 rmask;
    if (lo_row + 63 <= (int)Rv) rmask = ~0ull;
    else if (lo_row > (int)Rv)  rmask = 0ull;
    else                        rmask = (1ull << ((int)Rv - lo_row + 1)) - 1ull;
    s_kept[lane] = (~sup) & rmask;
  }
  __syncthreads();

  // zero-fill this image's output (d_out is poisoned before every launch)
  for (int x = t; x < POSTN*5; x += 1024) out[(size_t)b*POSTN*5 + x] = 0.0f;
  for (int x = t; x < POSTN;   x += 1024) out[(size_t)NB*POSTN*5 + b*POSTN + x] = 0.0f;
  if (t < 32) pref[t] = (u32)__popcll(s_kept[t]);
  __syncthreads();
  if (t == 0){
    u32 run = 0;
    for (int w = 0; w < 32; ++w){ u32 tv = pref[w]; pref[w] = run; run += tv; }
  }
  __syncthreads();
  for (int i = t; i < NCAND; i += 1024){
    u64 kw = s_kept[i >> 6];
    if ((kw >> (i & 63)) & 1ull){
      u32 rank = pref[i >> 6] + (u32)__popcll(kw & ((1ull << (i & 63)) - 1ull));
      if (rank < POSTN){
        const float* bp = sbox + ((size_t)(b*NCAND + i))*5;
        float* op = out + ((size_t)(b*POSTN + rank))*5;
        op[0]=bp[0]; op[1]=bp[1]; op[2]=bp[2]; op[3]=bp[3]; op[4]=bp[4];
        out[(size_t)NB*POSTN*5 + b*POSTN + rank] = sscore[b*NCAND + i];
      }
    }
  }
}

// ---------------------------------------------------------------------------
extern "C" void kernel_launch(void* const* d_in, const int* in_sizes, int n_in,
                              void* d_out, int out_size, void* d_ws, size_t ws_size,
                              hipStream_t stream)
{
  (void)out_size; (void)ws_size;
  const float *obj[4] = {nullptr,nullptr,nullptr,nullptr};
  const float *dlt[4] = {nullptr,nullptr,nullptr,nullptr};
  const float *anchors = nullptr;
  for (int i = 0; i < n_in; ++i){
    int s = in_sizes[i];
    const float* p = (const float*)d_in[i];
    switch (s){
      case 786432:  obj[0] = p; break;
      case 4718592: dlt[0] = p; break;
      case 196608:  obj[1] = p; break;
      case 1179648: dlt[1] = p; break;
      case 49152:   obj[2] = p; break;
      case 294912:  dlt[2] = p; break;
      case 12288:   obj[3] = p; break;
      case 73728:   dlt[3] = p; break;
      case 5222400: anchors = p; break;
      default: break;
    }
  }

  char* wsb = (char*)d_ws;
  size_t off = 0;
  auto alloc = [&](size_t bytes)->void*{
    size_t cur = (off + 255) & ~(size_t)255;
    off = cur + bytes;
    return (void*)(wsb + cur);
  };
  int*   cand_j = (int*)  alloc(16*KSEL*sizeof(int));
  float* cscore = (float*)alloc((size_t)NB*NCAND*sizeof(float));
  u32*   csmono = (u32*)  alloc((size_t)NB*NCAND*sizeof(u32));
  u64*   ctb    = (u64*)  alloc((size_t)NB*NCAND*sizeof(u64));
  float* cbox   = (float*)alloc((size_t)NB*NCAND*5*sizeof(float));
  u8*    cvalid = (u8*)   alloc((size_t)NB*NCAND);
  float* sscore = (float*)alloc((size_t)NB*NCAND*sizeof(float));
  float* sbox   = (float*)alloc((size_t)NB*NCAND*5*sizeof(float));
  u8*    svalid = (u8*)   alloc((size_t)NB*NCAND);
  float* geom   = (float*)alloc((size_t)NB*NCAND*16*sizeof(float));
  u64*   maskp  = (u64*)  alloc((size_t)NB*NCAND*32*sizeof(u64));
  u32*   plist  = (u32*)  alloc((size_t)PAIR_CAP*sizeof(u32));
  u32*   pcount = (u32*)  alloc(sizeof(u32));
  u32*   ghist  = (u32*)  alloc((size_t)K1_BLOCKS*BINS*sizeof(u32));
  u64*   gtie   = (u64*)  alloc((size_t)16*EQCAP*sizeof(u64));
  u32*   gb0    = (u32*)  alloc(16*sizeof(u32));
  u32*   gcA    = (u32*)  alloc(16*sizeof(u32));
  u32*   emitc  = (u32*)  alloc(16*sizeof(u32));
  u32*   tiec   = (u32*)  alloc(16*sizeof(u32));

  hipMemsetAsync(pcount, 0, sizeof(u32), stream);
  hipMemsetAsync(maskp, 0, (size_t)NB*NCAND*32*sizeof(u64), stream);

  hipLaunchKernelGGL(k1a_hist, dim3(K1_BLOCKS), dim3(1024), 0, stream,
                     obj[0], obj[1], obj[2], obj[3], ghist);
  hipLaunchKernelGGL(k1b_thresh, dim3(16), dim3(1024), 0, stream,
                     ghist, gb0, gcA, emitc, tiec);
  hipLaunchKernelGGL(k1c_classify, dim3(K1_BLOCKS), dim3(1024), 0, stream,
                     obj[0], obj[1], obj[2], obj[3], gb0, emitc, tiec,
                     cand_j, gtie);
  hipLaunchKernelGGL(k1d_tie, dim3(16), dim3(1024), 0, stream,
                     gtie, tiec, gcA, emitc, cand_j);
  hipLaunchKernelGGL(k2_decode, dim3(32), dim3(256), 0, stream,
                     obj[0], obj[1], obj[2], obj[3],
                     dlt[0], dlt[1], dlt[2], dlt[3],
                     anchors, cand_j, cscore, csmono, ctb, cbox, cvalid);
  hipLaunchKernelGGL(k3_sort, dim3(4), dim3(1024), 0, stream,
                     csmono, ctb, cscore, cbox, cvalid, sscore, sbox, geom, svalid);
  hipLaunchKernelGGL(k4a_aabb, dim3(K4A_BLOCKS), dim3(256), 0, stream,
                     geom, plist, pcount);
  hipLaunchKernelGGL(k4b_clip, dim3(256), dim3(256), 0, stream,
                     geom, plist, pcount, maskp);
  hipLaunchKernelGGL(k5_nms_out, dim3(4), dim3(1024), 0, stream,
                     maskp, svalid, sbox, sscore, (float*)d_out);
}

// Round 10
// 277.092 us; speedup vs baseline: 1.6306x; 1.1105x over previous
//
#include <hip/hip_runtime.h>

typedef unsigned int u32;
typedef unsigned long long u64;
typedef unsigned char u8;

#define NB 4
#define T_ANCH 261120
#define NCAND 2048          // candidates per image (4 levels x 512)
#define KSEL 512
#define POSTN 512
#define LOG_MAXF 4.135166556742356f
#define NMS_TH 0.7f
#define LVL_OFF_F 8192.0f
#define BINS 4096           // top-12 bits of mono32
#define EQCAP 8192          // tie-bin capacity (expected ~300-700 occupants)
#define PAIR_CAP (1u<<20)   // 1M compacted pairs
#define K4A_BLOCKS 2048     // 4 i-rows (8192 pairs) per block -> 32 KB LDS
#define K4A_ROWS 4
#define K1_BLOCKS 256       // 64 chunk-blocks per image (48/12/3/1 per level)

__device__ __forceinline__ u32 mono32(float f){
  u32 u = __float_as_uint(f);
  return (u & 0x80000000u) ? ~u : (u | 0x80000000u);
}
__device__ __forceinline__ int lvl_hw(int lvl){ return 65536 >> (2*lvl); }
__device__ __forceinline__ int lvl_off(int lvl){
  return (lvl>0?196608:0) + (lvl>1?49152:0) + (lvl>2?12288:0);
}
// chunk-block mapping: bx in [0,256): b = bx>>6, c = bx&63
__device__ __forceinline__ void k1_map(int bx, int& b, int& lvl, int& ch){
  b = bx >> 6;
  int c = bx & 63;
  if (c < 48){ lvl = 0; ch = c; }
  else if (c < 60){ lvl = 1; ch = c - 48; }
  else if (c < 63){ lvl = 2; ch = c - 60; }
  else { lvl = 3; ch = 0; }
}

// ---------------------------------------------------------------------------
// K1a: per-chunk private histogram of mono32>>20. 256 blocks, 1 float4/thread.
// ---------------------------------------------------------------------------
__global__ __launch_bounds__(1024) void k1a_hist(
    const float* __restrict__ o0, const float* __restrict__ o1,
    const float* __restrict__ o2, const float* __restrict__ o3,
    u32* __restrict__ ghist)
{
  int b, lvl, ch;
  k1_map(blockIdx.x, b, lvl, ch);
  const float* ob = (lvl==0)?o0 : (lvl==1)?o1 : (lvl==2)?o2 : o3;
  int hw = lvl_hw(lvl);
  int size = 3*hw;
  int n4 = size >> 2;
  int i4 = ch*1024 + threadIdx.x;
  __shared__ u32 hist[BINS];
  for (int i = threadIdx.x; i < BINS; i += 1024) hist[i] = 0;
  __syncthreads();
  if (i4 < n4){
    float4 v = ((const float4*)(ob + (size_t)b*size))[i4];
    atomicAdd(&hist[mono32(v.x) >> 20], 1u);
    atomicAdd(&hist[mono32(v.y) >> 20], 1u);
    atomicAdd(&hist[mono32(v.z) >> 20], 1u);
    atomicAdd(&hist[mono32(v.w) >> 20], 1u);
  }
  __syncthreads();
  u32* out = ghist + (size_t)blockIdx.x*BINS;
  for (int i = threadIdx.x; i < BINS; i += 1024) out[i] = hist[i];
}

// ---------------------------------------------------------------------------
// K1b: reduce chunk histograms per (b,lvl); serial threshold walk -> b0,
// cntAbove; zero emit/tie counters.
// ---------------------------------------------------------------------------
__global__ __launch_bounds__(1024) void k1b_thresh(
    const u32* __restrict__ ghist, u32* __restrict__ gb0,
    u32* __restrict__ gcA, u32* __restrict__ emitcnt, u32* __restrict__ tiecnt)
{
  int bid = blockIdx.x;               // 16 = (b,lvl)
  int b = bid >> 2, lvl = bid & 3;
  int base_bx = b*64 + (lvl==0?0 : lvl==1?48 : lvl==2?60 : 63);
  int nch = (lvl==0?48 : lvl==1?12 : lvl==2?3 : 1);
  __shared__ u32 hist[BINS];
  __shared__ u32 coarse[64];
  int t = threadIdx.x;
  u32 c0=0,c1=0,c2=0,c3=0;
  for (int ch = 0; ch < nch; ++ch){
    const u32* h = ghist + (size_t)(base_bx+ch)*BINS;
    c0 += h[4*t+0]; c1 += h[4*t+1]; c2 += h[4*t+2]; c3 += h[4*t+3];
  }
  hist[4*t+0]=c0; hist[4*t+1]=c1; hist[4*t+2]=c2; hist[4*t+3]=c3;
  __syncthreads();
  if (t < 64){
    u32 s = 0;
    for (int z = 0; z < 64; ++z) s += hist[t*64 + z];
    coarse[t] = s;
  }
  __syncthreads();
  if (t == 0){
    u32 acc = 0;
    int cb = 63;
    while (acc + coarse[cb] < (u32)KSEL){ acc += coarse[cb]; --cb; }
    int z = cb*64 + 63;
    while (acc + hist[z] < (u32)KSEL){ acc += hist[z]; --z; }
    gb0[bid] = (u32)z;
    gcA[bid] = acc;
    emitcnt[bid] = 0;
    tiecnt[bid] = 0;
  }
}

// ---------------------------------------------------------------------------
// K1c: classify chunk elements vs b0. LDS lists + ONE global reservation per
// list per block. Emits PERMUTED index j = pix*3 + a (see R4 notes).
// ---------------------------------------------------------------------------
__global__ __launch_bounds__(1024) void k1c_classify(
    const float* __restrict__ o0, const float* __restrict__ o1,
    const float* __restrict__ o2, const float* __restrict__ o3,
    const u32* __restrict__ gb0,
    u32* __restrict__ emitcnt, u32* __restrict__ tiecnt,
    int* __restrict__ cand_j, u64* __restrict__ gtie)
{
  int b, lvl, ch;
  k1_map(blockIdx.x, b, lvl, ch);
  int bid16 = b*4 + lvl;
  const float* ob = (lvl==0)?o0 : (lvl==1)?o1 : (lvl==2)?o2 : o3;
  int hw = lvl_hw(lvl);
  int size = 3*hw;
  int n4 = size >> 2;
  int i4 = ch*1024 + threadIdx.x;

  __shared__ u32 dbuf[KSEL];
  __shared__ u64 tbuf[4096];
  __shared__ u32 dn, tn, dbase, tbase;
  if (threadIdx.x == 0){ dn = 0; tn = 0; }
  __syncthreads();

  u32 b0v = gb0[bid16];
  if (i4 < n4){
    float4 v = ((const float4*)(ob + (size_t)b*size))[i4];
    int L = i4 << 2;
    int a = L / hw;                 // hw % 4 == 0 -> same a for all 4
    int pix = L - a*hw;
    int j0 = pix*3 + a;
    float vv[4] = {v.x, v.y, v.z, v.w};
    #pragma unroll
    for (int q = 0; q < 4; ++q){
      u32 m = mono32(vv[q]);
      u32 bin = m >> 20;
      int j = j0 + 3*q;
      if (bin > b0v){
        u32 s = atomicAdd(&dn, 1u);
        if (s < (u32)KSEL) dbuf[s] = (u32)j;
      } else if (bin == b0v){
        u32 s = atomicAdd(&tn, 1u);
        if (s < 4096u) tbuf[s] = ((u64)m << 32) | (u32)(~(u32)j);
      }
    }
  }
  __syncthreads();
  if (threadIdx.x == 0){
    dbase = dn ? atomicAdd(&emitcnt[bid16], dn) : 0u;
    tbase = tn ? atomicAdd(&tiecnt[bid16], tn) : 0u;
  }
  __syncthreads();
  for (u32 x = threadIdx.x; x < dn; x += 1024){
    u32 s = dbase + x;
    if (s < (u32)KSEL) cand_j[bid16*KSEL + s] = (int)dbuf[x];
  }
  for (u32 x = threadIdx.x; x < tn; x += 1024){
    u32 s = tbase + x;
    if (s < (u32)EQCAP) gtie[(size_t)bid16*EQCAP + s] = tbuf[x];
  }
}

// ---------------------------------------------------------------------------
// K1d: O(n^2) exact rank-select on the tie set; append k = 512-cntAbove
// winners (LDS-aggregated, one global reservation).
// ---------------------------------------------------------------------------
__global__ __launch_bounds__(1024) void k1d_tie(
    const u64* __restrict__ gtie, const u32* __restrict__ tiecnt,
    const u32* __restrict__ gcA, u32* __restrict__ emitcnt,
    int* __restrict__ cand_j)
{
  int bid = blockIdx.x;               // 16
  __shared__ u64 eq[EQCAP];           // 64 KB
  __shared__ u32 wbuf[KSEL];
  __shared__ u32 wn, wbase;
  u32 n = tiecnt[bid]; if (n > (u32)EQCAP) n = (u32)EQCAP;
  u32 k = (u32)KSEL - gcA[bid];
  if (threadIdx.x == 0) wn = 0;
  for (u32 i = threadIdx.x; i < n; i += 1024) eq[i] = gtie[(size_t)bid*EQCAP + i];
  __syncthreads();
  for (u32 i = threadIdx.x; i < n; i += 1024){
    u64 ki = eq[i];
    u32 r = 0;
    for (u32 m = 0; m < n; ++m) r += (eq[m] > ki) ? 1u : 0u;
    if (r < k){
      u32 s = atomicAdd(&wn, 1u);
      if (s < (u32)KSEL) wbuf[s] = (u32)(~(u32)ki);
    }
  }
  __syncthreads();
  if (threadIdx.x == 0) wbase = wn ? atomicAdd(&emitcnt[bid], wn) : 0u;
  __syncthreads();
  for (u32 x = threadIdx.x; x < wn; x += 1024){
    u32 s = wbase + x;
    if (s < (u32)KSEL) cand_j[bid*KSEL + s] = (int)wbuf[x];
  }
}

// ---------------------------------------------------------------------------
// K2: decode the 8192 selected candidates; build sort keys.
// ---------------------------------------------------------------------------
__global__ __launch_bounds__(256) void k2_decode(
    const float* __restrict__ o0, const float* __restrict__ o1,
    const float* __restrict__ o2, const float* __restrict__ o3,
    const float* __restrict__ d0, const float* __restrict__ d1,
    const float* __restrict__ d2, const float* __restrict__ d3,
    const float* __restrict__ anchors,
    const int* __restrict__ cand_j,
    float* __restrict__ cscore, u32* __restrict__ csmono,
    u64* __restrict__ ctb, float* __restrict__ cbox, u8* __restrict__ cvalid)
{
  int c = blockIdx.x*256 + threadIdx.x;
  if (c >= NB*NCAND) return;
  int pair = c >> 9;          // (b,lvl) pair index
  int b = pair >> 2, lvl = pair & 3;
  int j = cand_j[c];
  int hw = lvl_hw(lvl);
  u32 pix = (u32)j / 3u;
  u32 a = (u32)j - pix*3u;
  const float* ob = (lvl==0)?o0 : (lvl==1)?o1 : (lvl==2)?o2 : o3;
  const float* dl = (lvl==0)?d0 : (lvl==1)?d1 : (lvl==2)?d2 : d3;

  float ov = ob[(size_t)(b*3 + (int)a)*hw + pix];
  size_t dbase = ((size_t)(b*3 + (int)a)*6)*(size_t)hw + pix;
  float dx  = dl[dbase + 0*(size_t)hw];
  float dy  = dl[dbase + 1*(size_t)hw];
  float dw  = dl[dbase + 2*(size_t)hw];
  float dh  = dl[dbase + 3*(size_t)hw];
  float dsn = dl[dbase + 4*(size_t)hw];
  float dcs = dl[dbase + 5*(size_t)hw];
  int tt = lvl_off(lvl) + j;
  const float* an = anchors + ((size_t)b*T_ANCH + tt)*5;
  float ax=an[0], ay=an[1], aw=an[2], ah=an[3], aa=an[4];
  dw = fminf(dw, LOG_MAXF); dh = fminf(dh, LOG_MAXF);
  float cx = ax + dx*aw;
  float cy = ay + dy*ah;
  float w  = aw * expf(dw);
  float h  = ah * expf(dh);
  float ang = aa + atan2f(dsn, dcs);
  double sd = 1.0 / (1.0 + exp(-(double)ov));
  float sc = (float)sd;
  bool valid = (w >= 1e-3f) && (h >= 1e-3f) && (sc >= 0.0f);
  cscore[c] = sc;
  csmono[c] = valid ? mono32(sc) : 0u;        // invalid => -inf (stable-sorted by tb)
  // tiebreak: level asc, obj desc, idx asc  (== reference positional order)
  ctb[c] = ((u64)lvl << 50) | ((u64)(u32)(~mono32(ov)) << 18) | (u64)(u32)j;
  cvalid[c] = valid ? 1 : 0;
  float* bb = cbox + (size_t)c*5;
  bb[0]=cx; bb[1]=cy; bb[2]=w; bb[3]=h; bb[4]=ang;
}

// ---------------------------------------------------------------------------
// K3: per-image stable-equivalent sort (score desc, tb asc) via bitonic in LDS,
// then gather sorted arrays + geometry. Also writes a PACKED AABB array
// (float4 per candidate) so k4a's j-sweep is fully coalesced.
// ---------------------------------------------------------------------------
__global__ __launch_bounds__(1024) void k3_sort(
    const u32* __restrict__ csmono, const u64* __restrict__ ctb,
    const float* __restrict__ cscore, const float* __restrict__ cbox,
    const u8* __restrict__ cvalid,
    float* __restrict__ sscore, float* __restrict__ sbox,
    float* __restrict__ geom, float4* __restrict__ aabb4,
    u8* __restrict__ svalid)
{
  int b = blockIdx.x;
  __shared__ u32 sm[NCAND];
  __shared__ u64 stb[NCAND];
  __shared__ u32 sid[NCAND];
  for (int k = threadIdx.x; k < NCAND; k += 1024){
    sm[k]  = csmono[b*NCAND + k];
    stb[k] = ctb[b*NCAND + k];
    sid[k] = (u32)k;
  }
  __syncthreads();
  for (int kk = 2; kk <= NCAND; kk <<= 1){
    for (int jj = kk >> 1; jj > 0; jj >>= 1){
      for (int i = threadIdx.x; i < NCAND; i += 1024){
        int ixj = i ^ jj;
        if (ixj > i){
          bool dirAsc = ((i & kk) == 0);
          u32 s1 = sm[i], s2 = sm[ixj];
          u64 t1 = stb[i], t2 = stb[ixj];
          bool before_ixj = (s2 > s1) || (s2 == s1 && t2 < t1);
          bool sw = dirAsc ? before_ixj : !before_ixj;
          if (sw){
            sm[i]=s2; sm[ixj]=s1;
            stb[i]=t2; stb[ixj]=t1;
            u32 tmp = sid[i]; sid[i]=sid[ixj]; sid[ixj]=tmp;
          }
        }
      }
      __syncthreads();
    }
  }
  for (int k = threadIdx.x; k < NCAND; k += 1024){
    int id = (int)sid[k];
    int gsrc = b*NCAND + id;
    int gdst = b*NCAND + k;
    float scv = cscore[gsrc];
    sscore[gdst] = scv;
    svalid[gdst] = cvalid[gsrc];
    float b0 = cbox[(size_t)gsrc*5+0], b1 = cbox[(size_t)gsrc*5+1];
    float b2 = cbox[(size_t)gsrc*5+2], b3 = cbox[(size_t)gsrc*5+3];
    float b4 = cbox[(size_t)gsrc*5+4];
    float* sb = sbox + (size_t)gdst*5;
    sb[0]=b0; sb[1]=b1; sb[2]=b2; sb[3]=b3; sb[4]=b4;
    int lvl = (int)((stb[k] >> 50) & 3ull);
    float offv = (float)lvl * LVL_OFF_F;
    float cx = b0 + offv, cy = b1 + offv, w=b2, h=b3, ang=b4;
    float cc = cosf(ang), sn = sinf(ang);
    float hx = 0.5f*w, hy = 0.5f*h;
    float x0 = cx + hx*cc - hy*sn, y0 = cy + hx*sn + hy*cc;
    float x1 = cx - hx*cc - hy*sn, y1 = cy - hx*sn + hy*cc;
    float x2 = cx - hx*cc + hy*sn, y2 = cy - hx*sn - hy*cc;
    float x3 = cx + hx*cc + hy*sn, y3 = cy + hx*sn - hy*cc;
    float minx = fminf(fminf(x0,x1),fminf(x2,x3));
    float maxx = fmaxf(fmaxf(x0,x1),fmaxf(x2,x3));
    float miny = fminf(fminf(y0,y1),fminf(y2,y3));
    float maxy = fmaxf(fmaxf(y0,y1),fmaxf(y2,y3));
    float* g = geom + (size_t)gdst*16;
    g[0]=minx; g[1]=maxx; g[2]=miny; g[3]=maxy; g[4]=w*h;
    g[5]=x0; g[6]=y0; g[7]=x1; g[8]=y1; g[9]=x2; g[10]=y2; g[11]=x3; g[12]=y3;
    aabb4[gdst] = make_float4(minx, maxx, miny, maxy);
  }
}

// ---------------------------------------------------------------------------
// K4a: AABB filter -> compacted pair list. 2048 blocks x 4 i-rows (8192
// pairs); packed aabb4 reads are fully coalesced (16B/lane stride-16), the
// 32 KB/image working set lives in L1. Worst-case LDS list (8192 entries,
// 32 KB), ONE global atomicAdd per block.
// ---------------------------------------------------------------------------
__global__ __launch_bounds__(256) void k4a_aabb(
    const float4* __restrict__ aabb4,
    u32* __restrict__ list, u32* __restrict__ gcount)
{
  __shared__ u32 lbuf[K4A_ROWS*NCAND];   // 32 KB
  __shared__ u32 lcnt, lbase;
  if (threadIdx.x == 0) lcnt = 0;
  __syncthreads();
  int img = blockIdx.x >> 9;               // 512 blocks per image
  int i0  = (blockIdx.x & 511) * K4A_ROWS;
  #pragma unroll
  for (int r = 0; r < K4A_ROWS; ++r){
    int i = i0 + r;
    float4 gi = aabb4[img*NCAND + i];      // uniform -> cache broadcast
    for (int j = threadIdx.x; j < NCAND; j += 256){
      bool pass = false;
      if (j > i){
        float4 gj = aabb4[img*NCAND + j];
        pass = !(gi.x > gj.y || gj.x > gi.y || gi.z > gj.w || gj.z > gi.w);
      }
      if (pass){
        u32 s = atomicAdd(&lcnt, 1u);
        lbuf[s] = (u32)((img << 22) | (i << 11) | j);
      }
    }
  }
  __syncthreads();
  if (threadIdx.x == 0) lbase = lcnt ? atomicAdd(gcount, lcnt) : 0u;
  __syncthreads();
  u32 n = lcnt, bs = lbase;
  for (u32 x = threadIdx.x; x < n; x += 256){
    u32 idx = bs + x;
    if (idx < PAIR_CAP) list[idx] = lbuf[x];
  }
}

// ---------------------------------------------------------------------------
// K4b: dense clip over the compacted list; scatter bits via atomicOr.
// ---------------------------------------------------------------------------
__device__ __forceinline__ void emit_pt(float* ox, float* oy, int oc, float x, float y){
  #pragma unroll
  for (int s = 0; s < 8; ++s) if (s == oc){ ox[s] = x; oy[s] = y; }
}

__device__ float quad_inter(const float* ca, const float* cb){
  float px[8], py[8];
  #pragma unroll
  for (int q = 0; q < 8; ++q){ px[q]=0.f; py[q]=0.f; }
  #pragma unroll
  for (int q = 0; q < 4; ++q){ px[q]=ca[2*q]; py[q]=ca[2*q+1]; }
  int cnt = 4;
  #pragma unroll
  for (int e = 0; e < 4; ++e){
    float p1x = cb[2*e],         p1y = cb[2*e+1];
    float p2x = cb[(2*e+2)&7],   p2y = cb[(2*e+3)&7];
    float ex = p2x-p1x, ey = p2y-p1y;
    float d[8];
    #pragma unroll
    for (int q = 0; q < 8; ++q) d[q] = ex*(py[q]-p1y) - ey*(px[q]-p1x);
    float ox[8], oy[8];
    #pragma unroll
    for (int q = 0; q < 8; ++q){ ox[q]=0.f; oy[q]=0.f; }
    int oc = 0;
    #pragma unroll
    for (int q = 0; q < 8; ++q){
      if (q < cnt){
        bool last = (q+1 >= cnt);
        float dn  = last ? d[0]  : d[(q+1)&7];
        bool in0 = (d[q] >= 0.0f), in1 = (dn >= 0.0f);
        if (in0){ emit_pt(ox,oy,oc,px[q],py[q]); oc++; }
        if (in0 != in1){
          float pnx = last ? px[0] : px[(q+1)&7];
          float pny = last ? py[0] : py[(q+1)&7];
          float den = d[q] - dn;
          float t = d[q] / ((den == 0.0f) ? 1.0f : den);
          emit_pt(ox,oy,oc, px[q] + t*(pnx-px[q]), py[q] + t*(pny-py[q]));
          oc++;
        }
      }
    }
    cnt = (oc > 8) ? 8 : oc;
    #pragma unroll
    for (int q = 0; q < 8; ++q){ px[q]=ox[q]; py[q]=oy[q]; }
  }
  if (cnt < 3) return 0.0f;
  float s = 0.0f;
  #pragma unroll
  for (int q = 0; q < 8; ++q){
    if (q < cnt){
      bool last = (q+1 >= cnt);
      float pnx = last ? px[0] : px[(q+1)&7];
      float pny = last ? py[0] : py[(q+1)&7];
      s += px[q]*pny - pnx*py[q];
    }
  }
  return 0.5f*fabsf(s);
}

__global__ __launch_bounds__(256) void k4b_clip(
    const float* __restrict__ geom, const u32* __restrict__ list,
    const u32* __restrict__ gcount, u64* __restrict__ mask)
{
  u32 count = *gcount;
  if (count > PAIR_CAP) count = PAIR_CAP;
  for (u32 idx = blockIdx.x*256 + threadIdx.x; idx < count; idx += gridDim.x*256){
    u32 gt = list[idx];
    int img = (int)(gt >> 22);
    int rem = (int)(gt & ((1u<<22)-1));
    int i = rem >> 11;
    int j = rem & (NCAND-1);
    const float* gi = geom + ((size_t)(img*NCAND + i))*16;
    const float* gj = geom + ((size_t)(img*NCAND + j))*16;
    float inter = quad_inter(gi+5, gj+5);
    float iou = inter / (gi[4] + gj[4] - inter + 1e-7f);
    if (iou > NMS_TH)
      atomicOr(&mask[((size_t)(img*NCAND + i))*32 + (j >> 6)], 1ull << (j & 63));
  }
}

// ---------------------------------------------------------------------------
// K5: sequential greedy suppression, sup in wave-0 registers, early exit at
// the 512th kept row (see R6 notes).
// ---------------------------------------------------------------------------
__global__ __launch_bounds__(1024) void k5_nms_out(
    const u64* __restrict__ mask, const u8* __restrict__ svalid,
    const float* __restrict__ sbox, const float* __restrict__ sscore,
    float* __restrict__ out)
{
  int b = blockIdx.x;
  __shared__ u64 buf[2][128*32];      // 64 KB double buffer
  __shared__ u64 s_kept[32];
  __shared__ u32 pref[32];
  __shared__ u32 s_done, s_R;
  int t = threadIdx.x;
  int wid = t >> 6, lane = t & 63;

  if (t == 0){ s_done = 0; s_R = NCAND - 1; }

  // sup init from svalid: lane l (l<32) builds word l; lanes 32-63 mirror.
  u32 slo = 0, shi = 0;
  if (wid == 0){
    int wl = lane & 31;
    u64 w = 0;
    for (int q = 0; q < 64; ++q)
      if (!svalid[b*NCAND + wl*64 + q]) w |= (1ull << q);
    slo = (u32)w; shi = (u32)(w >> 32);
  }
  // preload chunk 0 (all waves)
  {
    const u64* src = mask + ((size_t)b*NCAND)*32;
    for (int x = t; x < 128*32; x += 1024) buf[0][x] = src[x];
  }
  __syncthreads();

  u32 kcnt = 0;
  bool stopped = false;
  for (int c = 0; c < 16; ++c){
    if (wid != 0){
      if (c + 1 < 16){
        const u64* src = mask + ((size_t)(b*NCAND + (c+1)*128))*32;
        for (int x = t - 64; x < 128*32; x += (1024 - 64))
          buf[(c+1)&1][x] = src[x];
      }
    } else if (!stopped){
      const u64* ch = buf[c&1];
      for (int r8 = 0; r8 < 128 && !stopped; r8 += 8){
        u64 v[8];
        #pragma unroll
        for (int q = 0; q < 8; ++q) v[q] = ch[(r8+q)*32 + (lane & 31)];
        #pragma unroll
        for (int q = 0; q < 8; ++q){
          int gi = c*128 + r8 + q;
          int wi = gi >> 6;                       // wave-uniform
          u32 wlo = (u32)__builtin_amdgcn_readlane((int)slo, wi);
          u32 whi = (u32)__builtin_amdgcn_readlane((int)shi, wi);
          u64 w = ((u64)whi << 32) | wlo;
          u32 keep = (u32)((~w >> (gi & 63)) & 1ull);
          u64 vm = v[q] & (0ull - (u64)keep);     // branchless: keep ? v : 0
          slo |= (u32)vm; shi |= (u32)(vm >> 32);
          kcnt += keep;
          if (kcnt >= (u32)POSTN){                // 512th keep -> stop
            if (lane == 0){ s_done = 1; s_R = (u32)gi; }
            stopped = true;
            break;
          }
        }
      }
    }
    __syncthreads();
    if (s_done) break;
    __syncthreads();
  }
  // publish kept words, range-masked to rows <= R
  if (wid == 0 && lane < 32){
    u32 Rv = s_R;
    int lo_row = (int)lane * 64;
    u64 sup = ((u64)shi << 32) | slo;
    u64 rmask;
    if (lo_row + 63 <= (int)Rv) rmask = ~0ull;
    else if (lo_row > (int)Rv)  rmask = 0ull;
    else                        rmask = (1ull << ((int)Rv - lo_row + 1)) - 1ull;
    s_kept[lane] = (~sup) & rmask;
  }
  __syncthreads();

  // zero-fill this image's output (d_out is poisoned before every launch)
  for (int x = t; x < POSTN*5; x += 1024) out[(size_t)b*POSTN*5 + x] = 0.0f;
  for (int x = t; x < POSTN;   x += 1024) out[(size_t)NB*POSTN*5 + b*POSTN + x] = 0.0f;
  if (t < 32) pref[t] = (u32)__popcll(s_kept[t]);
  __syncthreads();
  if (t == 0){
    u32 run = 0;
    for (int w = 0; w < 32; ++w){ u32 tv = pref[w]; pref[w] = run; run += tv; }
  }
  __syncthreads();
  for (int i = t; i < NCAND; i += 1024){
    u64 kw = s_kept[i >> 6];
    if ((kw >> (i & 63)) & 1ull){
      u32 rank = pref[i >> 6] + (u32)__popcll(kw & ((1ull << (i & 63)) - 1ull));
      if (rank < POSTN){
        const float* bp = sbox + ((size_t)(b*NCAND + i))*5;
        float* op = out + ((size_t)(b*POSTN + rank))*5;
        op[0]=bp[0]; op[1]=bp[1]; op[2]=bp[2]; op[3]=bp[3]; op[4]=bp[4];
        out[(size_t)NB*POSTN*5 + b*POSTN + rank] = sscore[b*NCAND + i];
      }
    }
  }
}

// ---------------------------------------------------------------------------
extern "C" void kernel_launch(void* const* d_in, const int* in_sizes, int n_in,
                              void* d_out, int out_size, void* d_ws, size_t ws_size,
                              hipStream_t stream)
{
  (void)out_size; (void)ws_size;
  const float *obj[4] = {nullptr,nullptr,nullptr,nullptr};
  const float *dlt[4] = {nullptr,nullptr,nullptr,nullptr};
  const float *anchors = nullptr;
  for (int i = 0; i < n_in; ++i){
    int s = in_sizes[i];
    const float* p = (const float*)d_in[i];
    switch (s){
      case 786432:  obj[0] = p; break;
      case 4718592: dlt[0] = p; break;
      case 196608:  obj[1] = p; break;
      case 1179648: dlt[1] = p; break;
      case 49152:   obj[2] = p; break;
      case 294912:  dlt[2] = p; break;
      case 12288:   obj[3] = p; break;
      case 73728:   dlt[3] = p; break;
      case 5222400: anchors = p; break;
      default: break;
    }
  }

  char* wsb = (char*)d_ws;
  size_t off = 0;
  auto alloc = [&](size_t bytes)->void*{
    size_t cur = (off + 255) & ~(size_t)255;
    off = cur + bytes;
    return (void*)(wsb + cur);
  };
  int*   cand_j = (int*)  alloc(16*KSEL*sizeof(int));
  float* cscore = (float*)alloc((size_t)NB*NCAND*sizeof(float));
  u32*   csmono = (u32*)  alloc((size_t)NB*NCAND*sizeof(u32));
  u64*   ctb    = (u64*)  alloc((size_t)NB*NCAND*sizeof(u64));
  float* cbox   = (float*)alloc((size_t)NB*NCAND*5*sizeof(float));
  u8*    cvalid = (u8*)   alloc((size_t)NB*NCAND);
  float* sscore = (float*)alloc((size_t)NB*NCAND*sizeof(float));
  float* sbox   = (float*)alloc((size_t)NB*NCAND*5*sizeof(float));
  u8*    svalid = (u8*)   alloc((size_t)NB*NCAND);
  float* geom   = (float*)alloc((size_t)NB*NCAND*16*sizeof(float));
  float4* aabb4 = (float4*)alloc((size_t)NB*NCAND*sizeof(float4));
  u64*   maskp  = (u64*)  alloc((size_t)NB*NCAND*32*sizeof(u64));
  u32*   plist  = (u32*)  alloc((size_t)PAIR_CAP*sizeof(u32));
  u32*   pcount = (u32*)  alloc(sizeof(u32));
  u32*   ghist  = (u32*)  alloc((size_t)K1_BLOCKS*BINS*sizeof(u32));
  u64*   gtie   = (u64*)  alloc((size_t)16*EQCAP*sizeof(u64));
  u32*   gb0    = (u32*)  alloc(16*sizeof(u32));
  u32*   gcA    = (u32*)  alloc(16*sizeof(u32));
  u32*   emitc  = (u32*)  alloc(16*sizeof(u32));
  u32*   tiec   = (u32*)  alloc(16*sizeof(u32));

  hipMemsetAsync(pcount, 0, sizeof(u32), stream);
  hipMemsetAsync(maskp, 0, (size_t)NB*NCAND*32*sizeof(u64), stream);

  hipLaunchKernelGGL(k1a_hist, dim3(K1_BLOCKS), dim3(1024), 0, stream,
                     obj[0], obj[1], obj[2], obj[3], ghist);
  hipLaunchKernelGGL(k1b_thresh, dim3(16), dim3(1024), 0, stream,
                     ghist, gb0, gcA, emitc, tiec);
  hipLaunchKernelGGL(k1c_classify, dim3(K1_BLOCKS), dim3(1024), 0, stream,
                     obj[0], obj[1], obj[2], obj[3], gb0, emitc, tiec,
                     cand_j, gtie);
  hipLaunchKernelGGL(k1d_tie, dim3(16), dim3(1024), 0, stream,
                     gtie, tiec, gcA, emitc, cand_j);
  hipLaunchKernelGGL(k2_decode, dim3(32), dim3(256), 0, stream,
                     obj[0], obj[1], obj[2], obj[3],
                     dlt[0], dlt[1], dlt[2], dlt[3],
                     anchors, cand_j, cscore, csmono, ctb, cbox, cvalid);
  hipLaunchKernelGGL(k3_sort, dim3(4), dim3(1024), 0, stream,
                     csmono, ctb, cscore, cbox, cvalid, sscore, sbox, geom,
                     aabb4, svalid);
  hipLaunchKernelGGL(k4a_aabb, dim3(K4A_BLOCKS), dim3(256), 0, stream,
                     aabb4, plist, pcount);
  hipLaunchKernelGGL(k4b_clip, dim3(256), dim3(256), 0, stream,
                     geom, plist, pcount, maskp);
  hipLaunchKernelGGL(k5_nms_out, dim3(4), dim3(1024), 0, stream,
                     maskp, svalid, sbox, sscore, (float*)d_out);
}